// Round 2
// baseline (616.696 us; speedup 1.0000x reference)
//
#include <hip/hip_runtime.h>
#include <hip/hip_fp8.h>
#include <math.h>

// ---------------------------------------------------------------------------
// GATClassifier on MI355X.
//   1. CSR build over dst (histogram -> 3-phase scan -> dst-STRIPED scatter:
//      stripe = bid&7 so all writers of a col2 line / cursor[d] land on one
//      XCD; (src,dst) packed int2 + src-only col_s. R15: old scatter wrote
//      84MB HBM for 6.8MB payload (cross-XCD line ping-pong).
//   2. Per layer: MFMA GEMM h = (Ah+Al) @ bf16(B) — A split-bf16 (exact),
//      B plain bf16 (R14). LDS-staged A, double-buffered, 1 barrier/k-step,
//      64 rows/block. h stored bf16-hi + QUARTER-BLOCKED fp8 copy
//      Hf8q[q][n][64] (R16: 3.2MB/quarter fits one XCD's 4MB L2; flat 12.8MB
//      table thrashed all 8 L2s -> 62MB of refetch in agg8).
//      ealpha also quarter-blocked eaq[q][slot][2] so each quarter streams
//      only its slice. agg8q: wave=(node,quarter), 4 edge-groups x 16
//      channel-lanes, grid striped so bid&7 -> quarter=(x>>1) pins each
//      quarter's gathers to an XCD pair (heuristic only, never correctness).
//   3. Fused mean-pool + 32->1 linear (batch sorted -> binary search)
// History: R2 pool 383. R3 SGEMM 158x2. R4 agg 155x2. R5 gemm 140x2. R6 agg
// 131x2. R7 scan 111. R8 agg 87x2. R9 gemm 89x2. R10 agg 80x2. R11 agg 71x2.
// R12 gemm 57x2. R13 32-row dbuf REGRESSED -> R14 64-row dbuf + drop Bl.
// R15 striped int2 scatter (scatter 50us -> off top-5). R16 quartered agg8.
// NOTE: edge_index / batch are int32.
// ---------------------------------------------------------------------------

typedef __attribute__((ext_vector_type(8))) __bf16 bf16x8;
typedef __attribute__((ext_vector_type(4))) __bf16 bf16x4;
typedef __attribute__((ext_vector_type(2))) __bf16 bf16x2;
typedef __attribute__((ext_vector_type(4))) float f32x4;
typedef __attribute__((ext_vector_type(2))) float f32x2;

#define SCAN_CH 4  // elements per thread in the device-wide scan

__device__ inline unsigned char f32_to_fp8(float f) {
  __hip_fp8_e4m3 v(f);
  return (unsigned char)v.__x;
}
__device__ inline float fp8_to_f32(unsigned char u) {
  __hip_fp8_e4m3 v;
  v.__x = (__hip_fp8_storage_t)u;
  return (float)v;
}

// Decode 4 packed fp8-e4m3 bytes -> 4 floats, accumulate w * val into acc.
__device__ inline void fma_fp8x4(f32x4& acc, float w, unsigned int packed) {
#if defined(__has_builtin) && __has_builtin(__builtin_amdgcn_cvt_pk_f32_fp8)
  f32x2 lo = __builtin_amdgcn_cvt_pk_f32_fp8((int)packed, false);  // bytes 0,1
  f32x2 hi = __builtin_amdgcn_cvt_pk_f32_fp8((int)packed, true);   // bytes 2,3
  acc[0] += w * lo[0];
  acc[1] += w * lo[1];
  acc[2] += w * hi[0];
  acc[3] += w * hi[1];
#else
  acc[0] += w * fp8_to_f32((unsigned char)(packed & 0xff));
  acc[1] += w * fp8_to_f32((unsigned char)((packed >> 8) & 0xff));
  acc[2] += w * fp8_to_f32((unsigned char)((packed >> 16) & 0xff));
  acc[3] += w * fp8_to_f32((unsigned char)(packed >> 24));
#endif
}

// ---------------- CSR build ----------------
__global__ __launch_bounds__(256) void k_init_deg(int* deg, int N) {
  int n = blockIdx.x * 256 + threadIdx.x;
  if (n < N) deg[n] = 1;  // self-loop
}

__global__ __launch_bounds__(256) void k_count_deg(const int* __restrict__ ei,
                                                   int E, int* deg) {
  int e = blockIdx.x * 256 + threadIdx.x;
  if (e < E) atomicAdd(&deg[ei[E + e]], 1);
}

// --- 3-phase exclusive scan (R8: old single-block scan was 111us on 1 CU) ---
__global__ __launch_bounds__(256) void k_scan_partial(const int* __restrict__ deg,
                                                      int* __restrict__ blockSums,
                                                      int N) {
  __shared__ int sh[256];
  int t = threadIdx.x, b = blockIdx.x;
  int base = (b * 256 + t) * SCAN_CH;
  int s = 0;
#pragma unroll
  for (int j = 0; j < SCAN_CH; j++) {
    int idx = base + j;
    if (idx < N) s += deg[idx];
  }
  sh[t] = s;
  __syncthreads();
  for (int off = 128; off > 0; off >>= 1) {
    if (t < off) sh[t] += sh[t + off];
    __syncthreads();
  }
  if (t == 0) blockSums[b] = sh[0];
}

__global__ __launch_bounds__(256) void k_scan_blocksums(
    const int* __restrict__ blockSums, int* __restrict__ blockOffs,
    int* __restrict__ rowptr, int nb, int N) {
  __shared__ int sh[256];
  int t = threadIdx.x;
  int v = (t < nb) ? blockSums[t] : 0;
  sh[t] = v;
  __syncthreads();
  for (int off = 1; off < 256; off <<= 1) {
    int u = (t >= off) ? sh[t - off] : 0;
    __syncthreads();
    sh[t] += u;
    __syncthreads();
  }
  if (t < nb) blockOffs[t] = sh[t] - v;  // exclusive
  if (t == nb - 1) rowptr[N] = sh[t];    // total
}

__global__ __launch_bounds__(256) void k_scan_final(const int* __restrict__ deg,
                                                    const int* __restrict__ blockOffs,
                                                    int* __restrict__ rowptr,
                                                    int* __restrict__ cursor, int N) {
  __shared__ int sh[256];
  int t = threadIdx.x, b = blockIdx.x;
  int base = (b * 256 + t) * SCAN_CH;
  int vals[SCAN_CH];
  int s = 0;
#pragma unroll
  for (int j = 0; j < SCAN_CH; j++) {
    int idx = base + j;
    vals[j] = (idx < N) ? deg[idx] : 0;
    s += vals[j];
  }
  sh[t] = s;
  __syncthreads();
  for (int off = 1; off < 256; off <<= 1) {
    int u = (t >= off) ? sh[t - off] : 0;
    __syncthreads();
    sh[t] += u;
    __syncthreads();
  }
  int run = blockOffs[b] + sh[t] - s;  // exclusive prefix for this thread
#pragma unroll
  for (int j = 0; j < SCAN_CH; j++) {
    int idx = base + j;
    if (idx < N) {
      rowptr[idx] = run;
      cursor[idx] = run;
      run += vals[j];
    }
  }
}

// dst-striped scatter (R15). Grid = 8 stripes x nch chunks; stripe = bid&7
// (matches the HW's round-robin block->XCD mapping, so all writes/atomics
// for a given dst land on one XCD's L2 — heuristic only, never a
// correctness dependence). Packed int2 store + src-only col_s (R16: agg
// reads src without dragging dst bytes).
__global__ __launch_bounds__(256) void k_scatter2(const int* __restrict__ ei,
                                                  int E, int N, int* cursor,
                                                  int2* __restrict__ col2,
                                                  int* __restrict__ col_s,
                                                  int chunkSz) {
  int stripe = blockIdx.x & 7;
  int chunk = blockIdx.x >> 3;
  int lo = (int)(((long long)N * stripe) >> 3);
  int hi = (int)(((long long)N * (stripe + 1)) >> 3);
  int base = chunk * chunkSz;
  int end = base + chunkSz;
  int total = E + N;
  if (end > total) end = total;
  for (int i = base + threadIdx.x; i < end; i += 256) {
    int d = (i < E) ? ei[E + i] : (i - E);
    if (d < lo || d >= hi) continue;
    int s = (i < E) ? ei[i] : d;
    int pos = atomicAdd(&cursor[d], 1);
    col2[pos] = make_int2(s, d);
    col_s[pos] = s;
  }
}

// ---------------- split-cast preps ----------------
__global__ __launch_bounds__(256) void k_split(const float* __restrict__ in,
                                               __bf16* __restrict__ oh,
                                               __bf16* __restrict__ ol, int n4) {
  int i = blockIdx.x * 256 + threadIdx.x;
  if (i >= n4) return;
  float4 v = ((const float4*)in)[i];
  bf16x4 h, l;
  h[0] = (__bf16)v.x; l[0] = (__bf16)(v.x - (float)h[0]);
  h[1] = (__bf16)v.y; l[1] = (__bf16)(v.y - (float)h[1]);
  h[2] = (__bf16)v.z; l[2] = (__bf16)(v.z - (float)h[2]);
  h[3] = (__bf16)v.w; l[3] = (__bf16)(v.w - (float)h[3]);
  ((bf16x4*)oh)[i] = h;
  ((bf16x4*)ol)[i] = l;
}

// W [K][Nc] fp32 -> WT [Nc][K] plain bf16 (R14: Bl dropped — B-bytes were
// the binding GEMM resource; h-error 1.6e-3 washes to ~2e-5 at output).
__global__ __launch_bounds__(256) void k_wprep(const float* __restrict__ W,
                                               __bf16* __restrict__ WTh,
                                               int K, int Nc) {
  int i = blockIdx.x * 256 + threadIdx.x;  // i = n*K + k
  if (i >= K * Nc) return;
  int n = i / K, k = i - n * K;
  WTh[i] = (__bf16)W[k * Nc + n];
}

// ---------------- LDS-shared MFMA GEMM (layers 1/2, R14) -----------------
// C = (Ah+Al) @ Bh. Block = 64 rows x 256 cols. A-tile double-buffered in
// LDS, 1 barrier/k-step. Per k-step per wave: 4 B-loads + 32 MFMAs.
// Cf8 written QUARTER-BLOCKED: Hf8q[q][m][64], q == wave (col0=wave*64).
// mfma_f32_16x16x32_bf16 (m89-verified): A: m=lane&15,k=quad*8+j;
// B: n=lane&15,k=quad*8+j (from WT); C/D: row=quad*4+reg, col=lane&15.
__global__ __launch_bounds__(256) void k_gemm_lds(
    const __bf16* __restrict__ Ah, const __bf16* __restrict__ Al,
    const __bf16* __restrict__ BTh,
    __bf16* __restrict__ Ch, unsigned char* __restrict__ Cf8, int M, int K) {
  constexpr int NcFull = 256;
  __shared__ __bf16 sAh[2][2048];  // [buf][(mt*4+kq)*16+l16][8]
  __shared__ __bf16 sAl[2][2048];
  int tid = threadIdx.x;
  int lane = tid & 63, wave = tid >> 6;
  int quad = lane >> 4, l16 = lane & 15;
  int m0 = blockIdx.x * 64;
  int col0 = wave * 64;
  // staging map: thread t -> row sr = t>>2 (0..63), k-quad skq = t&3
  int sr = tid >> 2, skq = tid & 3;
  int slot8 = (((sr >> 4) * 4 + skq) * 16 + (sr & 15)) * 8;
  int arow = min(m0 + sr, M - 1);  // clamp: rows >= M never stored
  const __bf16* agh = Ah + (size_t)arow * K + skq * 8;
  const __bf16* agl = Al + (size_t)arow * K + skq * 8;
  const __bf16* brh = BTh + (size_t)(col0 + l16) * K + quad * 8;
  f32x4 acc[4][4];  // [mt][nt]
#pragma unroll
  for (int mt = 0; mt < 4; mt++)
#pragma unroll
    for (int t = 0; t < 4; t++) acc[mt][t] = (f32x4){0.f, 0.f, 0.f, 0.f};
  // prologue: stage k0=0 into buf0
  *(bf16x8*)(sAh[0] + slot8) = *(const bf16x8*)agh;
  *(bf16x8*)(sAl[0] + slot8) = *(const bf16x8*)agl;
  __syncthreads();
  int buf = 0;
  for (int k0 = 0; k0 < K; k0 += 32, buf ^= 1) {
    bool more = (k0 + 32 < K);
    bf16x8 gh, gl;
    if (more) {  // prefetch A(k+1); has the whole compute phase to land
      gh = *(const bf16x8*)(agh + k0 + 32);
      gl = *(const bf16x8*)(agl + k0 + 32);
    }
    bf16x8 b_h[4];
#pragma unroll
    for (int t = 0; t < 4; t++)
      b_h[t] = *(const bf16x8*)(brh + (size_t)t * 16 * K + k0);
    const __bf16* rh = sAh[buf];
    const __bf16* rl = sAl[buf];
    bf16x8 a_h[4], a_l[4];
#pragma unroll
    for (int mt = 0; mt < 4; mt++) {
      int fi = ((mt * 4 + quad) * 16 + l16) * 8;
      a_h[mt] = *(const bf16x8*)(rh + fi);
      a_l[mt] = *(const bf16x8*)(rl + fi);
    }
#pragma unroll
    for (int t = 0; t < 4; t++) {
#pragma unroll
      for (int mt = 0; mt < 4; mt++) {
        acc[mt][t] = __builtin_amdgcn_mfma_f32_16x16x32_bf16(a_h[mt], b_h[t], acc[mt][t], 0, 0, 0);
        acc[mt][t] = __builtin_amdgcn_mfma_f32_16x16x32_bf16(a_l[mt], b_h[t], acc[mt][t], 0, 0, 0);
      }
    }
    // write A(k+1) to the alternate buffer (its readers were fenced by the
    // previous barrier); single barrier per step.
    if (more) {
      *(bf16x8*)(sAh[buf ^ 1] + slot8) = gh;
      *(bf16x8*)(sAl[buf ^ 1] + slot8) = gl;
    }
    __syncthreads();
  }
#pragma unroll
  for (int mt = 0; mt < 4; mt++) {
#pragma unroll
    for (int t = 0; t < 4; t++) {
#pragma unroll
      for (int r = 0; r < 4; r++) {
        int m = m0 + mt * 16 + quad * 4 + r;
        if (m < M) {
          int colq = t * 16 + l16;
          Ch[(size_t)m * NcFull + col0 + colq] = (__bf16)acc[mt][t][r];
          Cf8[((size_t)wave * M + m) * 64 + colq] = f32_to_fp8(acc[mt][t][r]);
        }
      }
    }
  }
}

// ---------------- MFMA GEMM, no-LDS (layer 3): (Ah+Al) @ Bh -------------
template <int NT, int MT>
__global__ __launch_bounds__(256) void k_gemm_split(
    const __bf16* __restrict__ Ah, const __bf16* __restrict__ Al,
    const __bf16* __restrict__ BTh,
    __bf16* __restrict__ Ch, int M, int K, int NcFull) {
  int lane = threadIdx.x & 63;
  int wave = threadIdx.x >> 6;
  int quad = lane >> 4;
  int l16 = lane & 15;
  int m0 = blockIdx.y * (64 * MT) + wave * (16 * MT);
  int col0 = blockIdx.x * (NT * 16);
  const __bf16* arh[MT];
  const __bf16* arl[MT];
#pragma unroll
  for (int mt = 0; mt < MT; mt++) {
    int am = min(m0 + mt * 16 + l16, M - 1);
    arh[mt] = Ah + (size_t)am * K + quad * 8;
    arl[mt] = Al + (size_t)am * K + quad * 8;
  }
  const __bf16* brh = BTh + (size_t)(col0 + l16) * K + quad * 8;
  f32x4 acc[MT][NT];
#pragma unroll
  for (int mt = 0; mt < MT; mt++)
#pragma unroll
    for (int t = 0; t < NT; t++) acc[mt][t] = (f32x4){0.f, 0.f, 0.f, 0.f};
  for (int k0 = 0; k0 < K; k0 += 32) {
    bf16x8 a_h[MT], a_l[MT], b_h[NT];
#pragma unroll
    for (int mt = 0; mt < MT; mt++) {
      a_h[mt] = *(const bf16x8*)(arh[mt] + k0);
      a_l[mt] = *(const bf16x8*)(arl[mt] + k0);
    }
#pragma unroll
    for (int t = 0; t < NT; t++)
      b_h[t] = *(const bf16x8*)(brh + (size_t)t * 16 * K + k0);
#pragma unroll
    for (int t = 0; t < NT; t++) {
#pragma unroll
      for (int mt = 0; mt < MT; mt++) {
        acc[mt][t] = __builtin_amdgcn_mfma_f32_16x16x32_bf16(a_h[mt], b_h[t], acc[mt][t], 0, 0, 0);
        acc[mt][t] = __builtin_amdgcn_mfma_f32_16x16x32_bf16(a_l[mt], b_h[t], acc[mt][t], 0, 0, 0);
      }
    }
  }
#pragma unroll
  for (int mt = 0; mt < MT; mt++) {
#pragma unroll
    for (int t = 0; t < NT; t++) {
#pragma unroll
      for (int r = 0; r < 4; r++) {
        int m = m0 + mt * 16 + quad * 4 + r;
        if (m < M)
          Ch[(size_t)m * NcFull + col0 + t * 16 + l16] = (__bf16)acc[mt][t][r];
      }
    }
  }
}

// ---------------- attention dots (bf16-hi) ----------------
__global__ __launch_bounds__(256) void k_att(const __bf16* __restrict__ Hh,
                                             const float* __restrict__ attS,
                                             const float* __restrict__ attD,
                                             float* __restrict__ aS,
                                             float* __restrict__ aD, int NH, int H) {
  int idx = blockIdx.x * 256 + threadIdx.x;
  if (idx >= NH) return;
  int h = idx % H;
  const bf16x8* hv = (const bf16x8*)(Hh + (size_t)idx * 32);
  const float* sv = attS + h * 32;
  const float* dv = attD + h * 32;
  float ss = 0.f, dd = 0.f;
#pragma unroll
  for (int k = 0; k < 4; k++) {
    bf16x8 a = hv[k];
#pragma unroll
    for (int j = 0; j < 8; j++) {
      float v = (float)a[j];
      ss += v * sv[k * 8 + j];
      dd += v * dv[k * 8 + j];
    }
  }
  aS[idx] = ss;
  aD[idx] = dd;
}

// ---------------- dense edge-parallel alpha (R12/R16) ----------------
// Output QUARTER-BLOCKED: eaq[q][e][2 heads] (4B per slot per quarter) so
// each agg quarter-wave streams only its own 3.4MB slice.
__global__ __launch_bounds__(256) void k_edge_alpha8(
    const float* __restrict__ aS, const float* __restrict__ aD,
    const int2* __restrict__ col2,
    __bf16* __restrict__ eaq, int M) {
  int e = blockIdx.x * 256 + threadIdx.x;
  if (e >= M) return;
  int2 sd = col2[e];
  const float* ap = aS + (size_t)sd.x * 8;
  const float* dp = aD + (size_t)sd.y * 8;
  float ev[8];
#pragma unroll
  for (int h = 0; h < 8; h++) {
    float x = ap[h] + dp[h];
    x = (x > 0.f) ? x : 0.2f * x;
    ev[h] = __expf(x);
  }
#pragma unroll
  for (int q = 0; q < 4; q++) {
    bf16x2 pr;
    pr[0] = (__bf16)ev[2 * q];
    pr[1] = (__bf16)ev[2 * q + 1];
    *(bf16x2*)(eaq + ((size_t)q * M + e) * 2) = pr;
  }
}

__global__ __launch_bounds__(256) void k_edge_alpha1(
    const float* __restrict__ aS, const float* __restrict__ aD,
    const int2* __restrict__ col2,
    __bf16* __restrict__ ealpha, int M) {
  int e = blockIdx.x * 256 + threadIdx.x;
  if (e >= M) return;
  int2 sd = col2[e];
  float x = aS[sd.x] + aD[sd.y];
  x = (x > 0.f) ? x : 0.2f * x;
  ealpha[e] = (__bf16)__expf(x);
}

// ---------------- GAT aggregation, H=8, channel-quartered (R16) ----------
// wave = (node, quarter). 4 edge-groups x 16 channel-lanes (64B = one L2
// line per edge per quarter). Grid: bid&7 = XCD slot, quarter = slot>>1 ->
// each quarter's 3.2MB Hf8q slice is gathered by exactly one XCD pair and
// stays L2-resident (12.8MB flat table thrashed 4MB L2s: 62MB refetch).
__global__ __launch_bounds__(256) void k_gat_agg8q(
    const unsigned char* __restrict__ Hf8q, const int* __restrict__ rowptr,
    const int* __restrict__ col_s, const __bf16* __restrict__ eaq,
    const float* __restrict__ bias, __bf16* __restrict__ outh,
    __bf16* __restrict__ outl, int N, int Mslots) {
  int x = blockIdx.x & 7;                       // XCD slot (heuristic)
  int q = x >> 1;                               // quarter 0..3
  int chunk = (blockIdx.x >> 3) * 2 + (x & 1);  // node-chunk within quarter
  int wave = threadIdx.x >> 6;
  int node = chunk * 4 + wave;
  if (node >= N) return;
  int lane = threadIdx.x & 63;
  int g = lane >> 4;   // edge-group 0..3
  int l = lane & 15;   // channel lane (4 ch x fp8)
  int hh = l >> 3;     // head-in-quarter 0..1
  int row0 = rowptr[node];
  int deg = rowptr[node + 1] - row0;
  const unsigned char* tab = Hf8q + (size_t)q * ((size_t)N * 64);
  const __bf16* ea = eaq + (size_t)q * ((size_t)Mslots * 2);
  f32x4 acc = (f32x4){0.f, 0.f, 0.f, 0.f};
  float den = 0.f;
  for (int i = 0; i < deg; i += 8) {  // 8 edges/iter: 2 outstanding gathers
    int e0 = i + g, e1 = i + 4 + g;
    int sl0 = row0 + min(e0, deg - 1);
    int sl1 = row0 + min(e1, deg - 1);
    int s0 = col_s[sl0];
    int s1 = col_s[sl1];
    float w0 = (e0 < deg) ? (float)ea[(size_t)sl0 * 2 + hh] : 0.f;
    float w1 = (e1 < deg) ? (float)ea[(size_t)sl1 * 2 + hh] : 0.f;
    unsigned int p0 = *(const unsigned int*)(tab + (size_t)s0 * 64 + l * 4);
    unsigned int p1 = *(const unsigned int*)(tab + (size_t)s1 * 64 + l * 4);
    den += w0 + w1;
    fma_fp8x4(acc, w0, p0);
    fma_fp8x4(acc, w1, p1);
  }
  // reduce across the 4 edge-groups (lane bits 4..5); w clamps guarantee
  // masked-out slots contribute exactly 0 (w=0, finite fp8 operand).
#pragma unroll
  for (int off = 16; off < 64; off <<= 1) {
#pragma unroll
    for (int j = 0; j < 4; j++) acc[j] += __shfl_xor(acc[j], off, 64);
    den += __shfl_xor(den, off, 64);
  }
  if (g == 0) {
    float rsv = 1.f / den;  // deg >= 1 (self-loop), den > 0
    float4 bv = *(const float4*)(bias + q * 64 + l * 4);
    bf16x4 hb, lb;
#pragma unroll
    for (int j = 0; j < 4; j++) {
      float v = acc[j] * rsv + ((const float*)&bv)[j];
      v = (v > 0.f) ? v : (__expf(v) - 1.f);  // ELU
      hb[j] = (__bf16)v;
      lb[j] = (__bf16)(v - (float)hb[j]);
    }
    *(bf16x4*)(outh + (size_t)node * 256 + q * 64 + l * 4) = hb;
    *(bf16x4*)(outl + (size_t)node * 256 + q * 64 + l * 4) = lb;
  }
}

// ---------------- GAT aggregation, H=1 (layer 3, fp32 out, no ELU) ------
__global__ __launch_bounds__(256) void k_gat_agg1(
    const __bf16* __restrict__ Hh, const int* __restrict__ rowptr,
    const int* __restrict__ col_s, const __bf16* __restrict__ ealpha,
    const float* __restrict__ bias, float* __restrict__ out, int N) {
  int wid = (blockIdx.x * blockDim.x + threadIdx.x) >> 6;
  int lane = threadIdx.x & 63;
  if (wid >= N) return;
  int n = wid;
  int row0 = rowptr[n];
  int deg = rowptr[n + 1] - row0;
  int eo = lane >> 3;
  int cl = lane & 7;
  f32x4 acc = (f32x4){0.f, 0.f, 0.f, 0.f};
  float den = 0.f;
  for (int i = eo; i < deg; i += 8) {
    int slot = row0 + i;
    int src = col_s[slot];
    float w = (float)ealpha[slot];
    den += w;
    bf16x4 hv = *(const bf16x4*)(Hh + (size_t)src * 32 + cl * 4);
#pragma unroll
    for (int j = 0; j < 4; j++) acc[j] += w * (float)hv[j];
  }
#pragma unroll
  for (int off = 8; off < 64; off <<= 1) {
#pragma unroll
    for (int j = 0; j < 4; j++) acc[j] += __shfl_xor(acc[j], off, 64);
    den += __shfl_xor(den, off, 64);
  }
  if (eo == 0) {
    float rsv = 1.f / den;
#pragma unroll
    for (int j = 0; j < 4; j++)
      out[(size_t)n * 32 + cl * 4 + j] = acc[j] * rsv + bias[cl * 4 + j];
  }
}

// ---------------- fused mean-pool + linear ----------------
__global__ __launch_bounds__(256) void k_pool_final(
    const float* __restrict__ h, const int* __restrict__ batch,
    const float* __restrict__ linW, const float* __restrict__ linb,
    float* __restrict__ out, int N) {
  __shared__ float sh[256];
  int g = blockIdx.x;
  int tid = threadIdx.x;
  int grp = tid >> 5, c = tid & 31;
  int lo = 0, hi = N;
  while (lo < hi) { int mid = (lo + hi) >> 1; if (batch[mid] < g) lo = mid + 1; else hi = mid; }
  int start = lo;
  hi = N;
  while (lo < hi) { int mid = (lo + hi) >> 1; if (batch[mid] < g + 1) lo = mid + 1; else hi = mid; }
  int end = lo;
  float acc = 0.f;
  for (int n = start + grp; n < end; n += 8) acc += h[(size_t)n * 32 + c];
  sh[tid] = acc;
  __syncthreads();
  if (tid < 32) {
    float s = 0.f;
#pragma unroll
    for (int j = 0; j < 8; j++) s += sh[j * 32 + tid];
    float v = s * linW[tid];
#pragma unroll
    for (int off = 16; off > 0; off >>= 1) v += __shfl_xor(v, off, 64);
    if (tid == 0) {
      float cnt = (float)(end - start);
      out[g] = v / fmaxf(cnt, 1.f) + linb[0];
    }
  }
}

extern "C" void kernel_launch(void* const* d_in, const int* in_sizes, int n_in,
                              void* d_out, int out_size, void* d_ws, size_t ws_size,
                              hipStream_t stream) {
  const float* x = (const float*)d_in[0];
  const int* ei = (const int*)d_in[1];
  const int* batch = (const int*)d_in[2];
  const float* W1 = (const float*)d_in[3];
  const float* as1 = (const float*)d_in[4];
  const float* ad1 = (const float*)d_in[5];
  const float* b1 = (const float*)d_in[6];
  const float* W2 = (const float*)d_in[7];
  const float* as2 = (const float*)d_in[8];
  const float* ad2 = (const float*)d_in[9];
  const float* b2 = (const float*)d_in[10];
  const float* W3 = (const float*)d_in[11];
  const float* as3 = (const float*)d_in[12];
  const float* ad3 = (const float*)d_in[13];
  const float* b3 = (const float*)d_in[14];
  const float* linW = (const float*)d_in[15];
  const float* linb = (const float*)d_in[16];

  const int N = in_sizes[0] / 256;
  const int E = in_sizes[1] / 2;
  const int NUM_GRAPHS = 64;
  float* out = (float*)d_out;

  char* ws = (char*)d_ws;
  size_t off = 0;
  auto alloc = [&](size_t bytes) -> void* {
    void* p = ws + off;
    off += (bytes + 255) & ~(size_t)255;
    return p;
  };
  __bf16* Hh = (__bf16*)alloc((size_t)N * 256 * 2);  // GEMM h out (bf16-hi)
  unsigned char* Hf8 = (unsigned char*)alloc((size_t)N * 256);  // fp8, quartered
  __bf16* Ah = (__bf16*)alloc((size_t)N * 256 * 2);  // GEMM A in (hi)
  __bf16* Al = (__bf16*)alloc((size_t)N * 256 * 2);  //           (lo)
  __bf16* ealpha = (__bf16*)alloc((size_t)(E + N) * 8 * 2);  // eaq / ealpha1
  float* aS = (float*)alloc((size_t)N * 8 * 4);
  float* aD = (float*)alloc((size_t)N * 8 * 4);
  int* deg = (int*)alloc((size_t)N * 4);
  int* rowptr = (int*)alloc((size_t)(N + 1) * 4);
  int* cursor = (int*)alloc((size_t)(N + 1) * 4);
  int2* col2 = (int2*)alloc((size_t)(E + N) * 8);  // packed (src,dst) per slot
  int* col_s = (int*)alloc((size_t)(E + N) * 4);   // src-only copy
  int* blockSums = (int*)alloc(256 * 4);
  int* blockOffs = (int*)alloc(256 * 4);
  __bf16* WT1h = (__bf16*)alloc(256 * 256 * 2);
  __bf16* WT2h = (__bf16*)alloc(256 * 256 * 2);
  __bf16* WT3h = (__bf16*)alloc(32 * 256 * 2);
  // h3agg reuses Ah (GEMM3 already consumed Ah/Al when agg3 writes)
  float* h3agg = (float*)Ah;

  // --- preps: x split + W transposes + CSR build ---
  k_split<<<(N * 64 + 255) / 256, 256, 0, stream>>>(x, Ah, Al, N * 64);
  k_wprep<<<(256 * 256 + 255) / 256, 256, 0, stream>>>(W1, WT1h, 256, 256);
  k_wprep<<<(256 * 256 + 255) / 256, 256, 0, stream>>>(W2, WT2h, 256, 256);
  k_wprep<<<(256 * 32 + 255) / 256, 256, 0, stream>>>(W3, WT3h, 256, 32);
  k_init_deg<<<(N + 255) / 256, 256, 0, stream>>>(deg, N);
  k_count_deg<<<(E + 255) / 256, 256, 0, stream>>>(ei, E, deg);
  const int nb = (N + 256 * SCAN_CH - 1) / (256 * SCAN_CH);  // 49 <= 256
  k_scan_partial<<<nb, 256, 0, stream>>>(deg, blockSums, N);
  k_scan_blocksums<<<1, 256, 0, stream>>>(blockSums, blockOffs, rowptr, nb, N);
  k_scan_final<<<nb, 256, 0, stream>>>(deg, blockOffs, rowptr, cursor, N);
  {
    const int totalItems = E + N;
    const int nch = 256;  // chunks per stripe; grid = 8*256 = 2048 blocks
    const int chunkSz = (totalItems + nch - 1) / nch;
    k_scatter2<<<8 * nch, 256, 0, stream>>>(ei, E, N, cursor, col2, col_s, chunkSz);
  }

  const int aggBlocks = (N + 3) / 4;
  const int nodeChunks = (N + 3) / 4;           // 4 nodes per agg8q block
  const int agg8qGrid = 8 * ((nodeChunks + 1) / 2);
  const int gemmBlocks = (N + 63) / 64;  // 64 rows/block, full 256-col width
  const int M = E + N;
  const int edgeBlocks = (M + 255) / 256;
  dim3 g3(1, (N + 63) / 64);

  // --- layer 1 ---
  k_gemm_lds<<<gemmBlocks, 256, 0, stream>>>(Ah, Al, WT1h, Hh, Hf8, N, 256);
  k_att<<<(N * 8 + 255) / 256, 256, 0, stream>>>(Hh, as1, ad1, aS, aD, N * 8, 8);
  k_edge_alpha8<<<edgeBlocks, 256, 0, stream>>>(aS, aD, col2, ealpha, M);
  k_gat_agg8q<<<agg8qGrid, 256, 0, stream>>>(Hf8, rowptr, col_s, ealpha, b1,
                                             Ah, Al, N, M);
  // --- layer 2 ---
  k_gemm_lds<<<gemmBlocks, 256, 0, stream>>>(Ah, Al, WT2h, Hh, Hf8, N, 256);
  k_att<<<(N * 8 + 255) / 256, 256, 0, stream>>>(Hh, as2, ad2, aS, aD, N * 8, 8);
  k_edge_alpha8<<<edgeBlocks, 256, 0, stream>>>(aS, aD, col2, ealpha, M);
  k_gat_agg8q<<<agg8qGrid, 256, 0, stream>>>(Hf8, rowptr, col_s, ealpha, b2,
                                             Ah, Al, N, M);
  // --- layer 3 (H=1, bf16 gather) ---
  k_gemm_split<2, 1><<<g3, 256, 0, stream>>>(Ah, Al, WT3h, Hh, N, 256, 32);
  k_att<<<(N + 255) / 256, 256, 0, stream>>>(Hh, as3, ad3, aS, aD, N, 1);
  k_edge_alpha1<<<edgeBlocks, 256, 0, stream>>>(aS, aD, col2, ealpha, M);
  k_gat_agg1<<<aggBlocks, 256, 0, stream>>>(Hh, rowptr, col_s, ealpha, b3,
                                            h3agg, N);
  // --- pool + final ---
  k_pool_final<<<NUM_GRAPHS, 256, 0, stream>>>(h3agg, batch, linW, linb, out, N);
}

// Round 3
// 577.372 us; speedup vs baseline: 1.0681x; 1.0681x over previous
//
#include <hip/hip_runtime.h>
#include <hip/hip_fp8.h>
#include <math.h>

// ---------------------------------------------------------------------------
// GATClassifier on MI355X.
//   1. CSR build over dst (histogram -> 3-phase scan -> dst-STRIPED scatter:
//      stripe = bid&7 so all writers of a col2 line / cursor[d] land on one
//      XCD; (src,dst) packed int2 + src-only col_s. R15: old scatter wrote
//      84MB HBM for 6.8MB payload (cross-XCD line ping-pong).
//   2. Per layer: MFMA GEMM h = (Ah+Al) @ bf16(B) — A split-bf16 (exact),
//      B plain bf16 (R14). LDS-staged A, double-buffered, 1 barrier/k-step,
//      64 rows/block. h stored bf16-hi + QUARTER-BLOCKED fp8 copy
//      Hf8q[q][n][64] (R16: 3.2MB/quarter fits one XCD's 4MB L2; flat 12.8MB
//      table thrashed all 8 L2s -> 62MB refetch). ealpha quarter-blocked
//      eaq[q][slot][2]. R17: agg wave = 4 nodes x 1 quarter (16 lanes/node,
//      NO cross-group reduce, 4-deep unroll) — R16's wave=1 node-quarter
//      had 4x wave count with ~2 loop iters/wave; prologue+shfl-reduce+ELU
//      epilogue dominated (VALUBusy 67%, dur 2x WORSE despite fetch -44%).
//      Grid pinning bid&7 -> quarter=(slot>>1) kept (it delivered the fetch
//      drop; heuristic only, never correctness).
//   3. Fused mean-pool + 32->1 linear (batch sorted -> binary search)
// History: R2 pool 383. R3 SGEMM 158x2. R4 agg 155x2. R5 gemm 140x2. R6 agg
// 131x2. R7 scan 111. R8 agg 87x2. R9 gemm 89x2. R10 agg 80x2. R11 agg 71x2.
// R12 gemm 57x2. R13 32-row dbuf REGRESSED -> R14 64-row dbuf + drop Bl.
// R15 striped int2 scatter (scatter 50us -> off top-5; agg8 46.5x2).
// R16 quartered agg REGRESSED (102x2: per-wave overhead). R17 requartered.
// NOTE: edge_index / batch are int32.
// ---------------------------------------------------------------------------

typedef __attribute__((ext_vector_type(8))) __bf16 bf16x8;
typedef __attribute__((ext_vector_type(4))) __bf16 bf16x4;
typedef __attribute__((ext_vector_type(2))) __bf16 bf16x2;
typedef __attribute__((ext_vector_type(4))) float f32x4;
typedef __attribute__((ext_vector_type(2))) float f32x2;

#define SCAN_CH 4  // elements per thread in the device-wide scan

__device__ inline unsigned char f32_to_fp8(float f) {
  __hip_fp8_e4m3 v(f);
  return (unsigned char)v.__x;
}
__device__ inline float fp8_to_f32(unsigned char u) {
  __hip_fp8_e4m3 v;
  v.__x = (__hip_fp8_storage_t)u;
  return (float)v;
}

// Decode 4 packed fp8-e4m3 bytes -> 4 floats, accumulate w * val into acc.
__device__ inline void fma_fp8x4(f32x4& acc, float w, unsigned int packed) {
#if defined(__has_builtin) && __has_builtin(__builtin_amdgcn_cvt_pk_f32_fp8)
  f32x2 lo = __builtin_amdgcn_cvt_pk_f32_fp8((int)packed, false);  // bytes 0,1
  f32x2 hi = __builtin_amdgcn_cvt_pk_f32_fp8((int)packed, true);   // bytes 2,3
  acc[0] += w * lo[0];
  acc[1] += w * lo[1];
  acc[2] += w * hi[0];
  acc[3] += w * hi[1];
#else
  acc[0] += w * fp8_to_f32((unsigned char)(packed & 0xff));
  acc[1] += w * fp8_to_f32((unsigned char)((packed >> 8) & 0xff));
  acc[2] += w * fp8_to_f32((unsigned char)((packed >> 16) & 0xff));
  acc[3] += w * fp8_to_f32((unsigned char)(packed >> 24));
#endif
}

// ---------------- CSR build ----------------
__global__ __launch_bounds__(256) void k_init_deg(int* deg, int N) {
  int n = blockIdx.x * 256 + threadIdx.x;
  if (n < N) deg[n] = 1;  // self-loop
}

__global__ __launch_bounds__(256) void k_count_deg(const int* __restrict__ ei,
                                                   int E, int* deg) {
  int e = blockIdx.x * 256 + threadIdx.x;
  if (e < E) atomicAdd(&deg[ei[E + e]], 1);
}

// --- 3-phase exclusive scan (R8: old single-block scan was 111us on 1 CU) ---
__global__ __launch_bounds__(256) void k_scan_partial(const int* __restrict__ deg,
                                                      int* __restrict__ blockSums,
                                                      int N) {
  __shared__ int sh[256];
  int t = threadIdx.x, b = blockIdx.x;
  int base = (b * 256 + t) * SCAN_CH;
  int s = 0;
#pragma unroll
  for (int j = 0; j < SCAN_CH; j++) {
    int idx = base + j;
    if (idx < N) s += deg[idx];
  }
  sh[t] = s;
  __syncthreads();
  for (int off = 128; off > 0; off >>= 1) {
    if (t < off) sh[t] += sh[t + off];
    __syncthreads();
  }
  if (t == 0) blockSums[b] = sh[0];
}

__global__ __launch_bounds__(256) void k_scan_blocksums(
    const int* __restrict__ blockSums, int* __restrict__ blockOffs,
    int* __restrict__ rowptr, int nb, int N) {
  __shared__ int sh[256];
  int t = threadIdx.x;
  int v = (t < nb) ? blockSums[t] : 0;
  sh[t] = v;
  __syncthreads();
  for (int off = 1; off < 256; off <<= 1) {
    int u = (t >= off) ? sh[t - off] : 0;
    __syncthreads();
    sh[t] += u;
    __syncthreads();
  }
  if (t < nb) blockOffs[t] = sh[t] - v;  // exclusive
  if (t == nb - 1) rowptr[N] = sh[t];    // total
}

__global__ __launch_bounds__(256) void k_scan_final(const int* __restrict__ deg,
                                                    const int* __restrict__ blockOffs,
                                                    int* __restrict__ rowptr,
                                                    int* __restrict__ cursor, int N) {
  __shared__ int sh[256];
  int t = threadIdx.x, b = blockIdx.x;
  int base = (b * 256 + t) * SCAN_CH;
  int vals[SCAN_CH];
  int s = 0;
#pragma unroll
  for (int j = 0; j < SCAN_CH; j++) {
    int idx = base + j;
    vals[j] = (idx < N) ? deg[idx] : 0;
    s += vals[j];
  }
  sh[t] = s;
  __syncthreads();
  for (int off = 1; off < 256; off <<= 1) {
    int u = (t >= off) ? sh[t - off] : 0;
    __syncthreads();
    sh[t] += u;
    __syncthreads();
  }
  int run = blockOffs[b] + sh[t] - s;  // exclusive prefix for this thread
#pragma unroll
  for (int j = 0; j < SCAN_CH; j++) {
    int idx = base + j;
    if (idx < N) {
      rowptr[idx] = run;
      cursor[idx] = run;
      run += vals[j];
    }
  }
}

// dst-striped scatter (R15). Grid = 8 stripes x nch chunks; stripe = bid&7
// (matches the HW's round-robin block->XCD mapping, so all writes/atomics
// for a given dst land on one XCD's L2 — heuristic only, never a
// correctness dependence). Packed int2 store + src-only col_s (R16: agg
// reads src without dragging dst bytes).
__global__ __launch_bounds__(256) void k_scatter2(const int* __restrict__ ei,
                                                  int E, int N, int* cursor,
                                                  int2* __restrict__ col2,
                                                  int* __restrict__ col_s,
                                                  int chunkSz) {
  int stripe = blockIdx.x & 7;
  int chunk = blockIdx.x >> 3;
  int lo = (int)(((long long)N * stripe) >> 3);
  int hi = (int)(((long long)N * (stripe + 1)) >> 3);
  int base = chunk * chunkSz;
  int end = base + chunkSz;
  int total = E + N;
  if (end > total) end = total;
  for (int i = base + threadIdx.x; i < end; i += 256) {
    int d = (i < E) ? ei[E + i] : (i - E);
    if (d < lo || d >= hi) continue;
    int s = (i < E) ? ei[i] : d;
    int pos = atomicAdd(&cursor[d], 1);
    col2[pos] = make_int2(s, d);
    col_s[pos] = s;
  }
}

// ---------------- split-cast preps ----------------
__global__ __launch_bounds__(256) void k_split(const float* __restrict__ in,
                                               __bf16* __restrict__ oh,
                                               __bf16* __restrict__ ol, int n4) {
  int i = blockIdx.x * 256 + threadIdx.x;
  if (i >= n4) return;
  float4 v = ((const float4*)in)[i];
  bf16x4 h, l;
  h[0] = (__bf16)v.x; l[0] = (__bf16)(v.x - (float)h[0]);
  h[1] = (__bf16)v.y; l[1] = (__bf16)(v.y - (float)h[1]);
  h[2] = (__bf16)v.z; l[2] = (__bf16)(v.z - (float)h[2]);
  h[3] = (__bf16)v.w; l[3] = (__bf16)(v.w - (float)h[3]);
  ((bf16x4*)oh)[i] = h;
  ((bf16x4*)ol)[i] = l;
}

// W [K][Nc] fp32 -> WT [Nc][K] plain bf16 (R14: Bl dropped — B-bytes were
// the binding GEMM resource; h-error 1.6e-3 washes to ~2e-5 at output).
__global__ __launch_bounds__(256) void k_wprep(const float* __restrict__ W,
                                               __bf16* __restrict__ WTh,
                                               int K, int Nc) {
  int i = blockIdx.x * 256 + threadIdx.x;  // i = n*K + k
  if (i >= K * Nc) return;
  int n = i / K, k = i - n * K;
  WTh[i] = (__bf16)W[k * Nc + n];
}

// ---------------- LDS-shared MFMA GEMM (layers 1/2, R14) -----------------
// C = (Ah+Al) @ Bh. Block = 64 rows x 256 cols. A-tile double-buffered in
// LDS, 1 barrier/k-step. Per k-step per wave: 4 B-loads + 32 MFMAs.
// Cf8 written QUARTER-BLOCKED: Hf8q[q][m][64], q == wave (col0=wave*64).
// mfma_f32_16x16x32_bf16 (m89-verified): A: m=lane&15,k=quad*8+j;
// B: n=lane&15,k=quad*8+j (from WT); C/D: row=quad*4+reg, col=lane&15.
__global__ __launch_bounds__(256) void k_gemm_lds(
    const __bf16* __restrict__ Ah, const __bf16* __restrict__ Al,
    const __bf16* __restrict__ BTh,
    __bf16* __restrict__ Ch, unsigned char* __restrict__ Cf8, int M, int K) {
  constexpr int NcFull = 256;
  __shared__ __bf16 sAh[2][2048];  // [buf][(mt*4+kq)*16+l16][8]
  __shared__ __bf16 sAl[2][2048];
  int tid = threadIdx.x;
  int lane = tid & 63, wave = tid >> 6;
  int quad = lane >> 4, l16 = lane & 15;
  int m0 = blockIdx.x * 64;
  int col0 = wave * 64;
  // staging map: thread t -> row sr = t>>2 (0..63), k-quad skq = t&3
  int sr = tid >> 2, skq = tid & 3;
  int slot8 = (((sr >> 4) * 4 + skq) * 16 + (sr & 15)) * 8;
  int arow = min(m0 + sr, M - 1);  // clamp: rows >= M never stored
  const __bf16* agh = Ah + (size_t)arow * K + skq * 8;
  const __bf16* agl = Al + (size_t)arow * K + skq * 8;
  const __bf16* brh = BTh + (size_t)(col0 + l16) * K + quad * 8;
  f32x4 acc[4][4];  // [mt][nt]
#pragma unroll
  for (int mt = 0; mt < 4; mt++)
#pragma unroll
    for (int t = 0; t < 4; t++) acc[mt][t] = (f32x4){0.f, 0.f, 0.f, 0.f};
  // prologue: stage k0=0 into buf0
  *(bf16x8*)(sAh[0] + slot8) = *(const bf16x8*)agh;
  *(bf16x8*)(sAl[0] + slot8) = *(const bf16x8*)agl;
  __syncthreads();
  int buf = 0;
  for (int k0 = 0; k0 < K; k0 += 32, buf ^= 1) {
    bool more = (k0 + 32 < K);
    bf16x8 gh, gl;
    if (more) {  // prefetch A(k+1); has the whole compute phase to land
      gh = *(const bf16x8*)(agh + k0 + 32);
      gl = *(const bf16x8*)(agl + k0 + 32);
    }
    bf16x8 b_h[4];
#pragma unroll
    for (int t = 0; t < 4; t++)
      b_h[t] = *(const bf16x8*)(brh + (size_t)t * 16 * K + k0);
    const __bf16* rh = sAh[buf];
    const __bf16* rl = sAl[buf];
    bf16x8 a_h[4], a_l[4];
#pragma unroll
    for (int mt = 0; mt < 4; mt++) {
      int fi = ((mt * 4 + quad) * 16 + l16) * 8;
      a_h[mt] = *(const bf16x8*)(rh + fi);
      a_l[mt] = *(const bf16x8*)(rl + fi);
    }
#pragma unroll
    for (int t = 0; t < 4; t++) {
#pragma unroll
      for (int mt = 0; mt < 4; mt++) {
        acc[mt][t] = __builtin_amdgcn_mfma_f32_16x16x32_bf16(a_h[mt], b_h[t], acc[mt][t], 0, 0, 0);
        acc[mt][t] = __builtin_amdgcn_mfma_f32_16x16x32_bf16(a_l[mt], b_h[t], acc[mt][t], 0, 0, 0);
      }
    }
    // write A(k+1) to the alternate buffer (its readers were fenced by the
    // previous barrier); single barrier per step.
    if (more) {
      *(bf16x8*)(sAh[buf ^ 1] + slot8) = gh;
      *(bf16x8*)(sAl[buf ^ 1] + slot8) = gl;
    }
    __syncthreads();
  }
#pragma unroll
  for (int mt = 0; mt < 4; mt++) {
#pragma unroll
    for (int t = 0; t < 4; t++) {
#pragma unroll
      for (int r = 0; r < 4; r++) {
        int m = m0 + mt * 16 + quad * 4 + r;
        if (m < M) {
          int colq = t * 16 + l16;
          Ch[(size_t)m * NcFull + col0 + colq] = (__bf16)acc[mt][t][r];
          Cf8[((size_t)wave * M + m) * 64 + colq] = f32_to_fp8(acc[mt][t][r]);
        }
      }
    }
  }
}

// ---------------- MFMA GEMM, no-LDS (layer 3): (Ah+Al) @ Bh -------------
template <int NT, int MT>
__global__ __launch_bounds__(256) void k_gemm_split(
    const __bf16* __restrict__ Ah, const __bf16* __restrict__ Al,
    const __bf16* __restrict__ BTh,
    __bf16* __restrict__ Ch, int M, int K, int NcFull) {
  int lane = threadIdx.x & 63;
  int wave = threadIdx.x >> 6;
  int quad = lane >> 4;
  int l16 = lane & 15;
  int m0 = blockIdx.y * (64 * MT) + wave * (16 * MT);
  int col0 = blockIdx.x * (NT * 16);
  const __bf16* arh[MT];
  const __bf16* arl[MT];
#pragma unroll
  for (int mt = 0; mt < MT; mt++) {
    int am = min(m0 + mt * 16 + l16, M - 1);
    arh[mt] = Ah + (size_t)am * K + quad * 8;
    arl[mt] = Al + (size_t)am * K + quad * 8;
  }
  const __bf16* brh = BTh + (size_t)(col0 + l16) * K + quad * 8;
  f32x4 acc[MT][NT];
#pragma unroll
  for (int mt = 0; mt < MT; mt++)
#pragma unroll
    for (int t = 0; t < NT; t++) acc[mt][t] = (f32x4){0.f, 0.f, 0.f, 0.f};
  for (int k0 = 0; k0 < K; k0 += 32) {
    bf16x8 a_h[MT], a_l[MT], b_h[NT];
#pragma unroll
    for (int mt = 0; mt < MT; mt++) {
      a_h[mt] = *(const bf16x8*)(arh[mt] + k0);
      a_l[mt] = *(const bf16x8*)(arl[mt] + k0);
    }
#pragma unroll
    for (int t = 0; t < NT; t++)
      b_h[t] = *(const bf16x8*)(brh + (size_t)t * 16 * K + k0);
#pragma unroll
    for (int t = 0; t < NT; t++) {
#pragma unroll
      for (int mt = 0; mt < MT; mt++) {
        acc[mt][t] = __builtin_amdgcn_mfma_f32_16x16x32_bf16(a_h[mt], b_h[t], acc[mt][t], 0, 0, 0);
        acc[mt][t] = __builtin_amdgcn_mfma_f32_16x16x32_bf16(a_l[mt], b_h[t], acc[mt][t], 0, 0, 0);
      }
    }
  }
#pragma unroll
  for (int mt = 0; mt < MT; mt++) {
#pragma unroll
    for (int t = 0; t < NT; t++) {
#pragma unroll
      for (int r = 0; r < 4; r++) {
        int m = m0 + mt * 16 + quad * 4 + r;
        if (m < M)
          Ch[(size_t)m * NcFull + col0 + t * 16 + l16] = (__bf16)acc[mt][t][r];
      }
    }
  }
}

// ---------------- attention dots (bf16-hi) ----------------
__global__ __launch_bounds__(256) void k_att(const __bf16* __restrict__ Hh,
                                             const float* __restrict__ attS,
                                             const float* __restrict__ attD,
                                             float* __restrict__ aS,
                                             float* __restrict__ aD, int NH, int H) {
  int idx = blockIdx.x * 256 + threadIdx.x;
  if (idx >= NH) return;
  int h = idx % H;
  const bf16x8* hv = (const bf16x8*)(Hh + (size_t)idx * 32);
  const float* sv = attS + h * 32;
  const float* dv = attD + h * 32;
  float ss = 0.f, dd = 0.f;
#pragma unroll
  for (int k = 0; k < 4; k++) {
    bf16x8 a = hv[k];
#pragma unroll
    for (int j = 0; j < 8; j++) {
      float v = (float)a[j];
      ss += v * sv[k * 8 + j];
      dd += v * dv[k * 8 + j];
    }
  }
  aS[idx] = ss;
  aD[idx] = dd;
}

// ---------------- dense edge-parallel alpha (R12/R16) ----------------
// Output QUARTER-BLOCKED: eaq[q][e][2 heads] (4B per slot per quarter) so
// each agg quarter-wave streams only its own 3.4MB slice.
__global__ __launch_bounds__(256) void k_edge_alpha8(
    const float* __restrict__ aS, const float* __restrict__ aD,
    const int2* __restrict__ col2,
    __bf16* __restrict__ eaq, int M) {
  int e = blockIdx.x * 256 + threadIdx.x;
  if (e >= M) return;
  int2 sd = col2[e];
  const float* ap = aS + (size_t)sd.x * 8;
  const float* dp = aD + (size_t)sd.y * 8;
  float ev[8];
#pragma unroll
  for (int h = 0; h < 8; h++) {
    float x = ap[h] + dp[h];
    x = (x > 0.f) ? x : 0.2f * x;
    ev[h] = __expf(x);
  }
#pragma unroll
  for (int q = 0; q < 4; q++) {
    bf16x2 pr;
    pr[0] = (__bf16)ev[2 * q];
    pr[1] = (__bf16)ev[2 * q + 1];
    *(bf16x2*)(eaq + ((size_t)q * M + e) * 2) = pr;
  }
}

__global__ __launch_bounds__(256) void k_edge_alpha1(
    const float* __restrict__ aS, const float* __restrict__ aD,
    const int2* __restrict__ col2,
    __bf16* __restrict__ ealpha, int M) {
  int e = blockIdx.x * 256 + threadIdx.x;
  if (e >= M) return;
  int2 sd = col2[e];
  float x = aS[sd.x] + aD[sd.y];
  x = (x > 0.f) ? x : 0.2f * x;
  ealpha[e] = (__bf16)__expf(x);
}

// ---------------- GAT aggregation, H=8, channel-quartered (R17) ----------
// wave = 4 NODES x one 64-channel quarter. lane = group g (node) * 16 +
// channel-lane l. Each 16-lane group walks its own node's edges serially —
// NO cross-group reduce (den replicated per-lane, as R15). 4-deep unroll =
// 4 outstanding 256B gathers/wave (each inst spans the 4 groups' rows).
// Tail slots clamp to w=0 (exact zero contribution). Grid: bid&7 = XCD
// slot, quarter = slot>>1 -> each quarter's 3.2MB Hf8q slice pinned to one
// XCD pair, L2-resident (R16 proved: fetch 95.9 -> 53.8MB).
__global__ __launch_bounds__(256) void k_gat_agg8q(
    const unsigned char* __restrict__ Hf8q, const int* __restrict__ rowptr,
    const int* __restrict__ col_s, const __bf16* __restrict__ eaq,
    const float* __restrict__ bias, __bf16* __restrict__ outh,
    __bf16* __restrict__ outl, int N, int Mslots) {
  int slot = blockIdx.x & 7;                    // XCD slot (heuristic)
  int q = slot >> 1;                            // quarter 0..3
  int chunk = (blockIdx.x >> 3) * 2 + (slot & 1);  // 16-node chunk
  int wave = threadIdx.x >> 6;
  int lane = threadIdx.x & 63;
  int g = lane >> 4;   // node-group 0..3
  int l = lane & 15;   // channel lane (4 ch x fp8)
  int hh = l >> 3;     // head-in-quarter 0..1
  int node = chunk * 16 + wave * 4 + g;
  bool active = (node < N);
  int nc = active ? node : (N - 1);
  int row0 = rowptr[nc];
  int deg = active ? (rowptr[nc + 1] - row0) : 0;
  int degmax = deg;
  degmax = max(degmax, __shfl_xor(degmax, 16, 64));
  degmax = max(degmax, __shfl_xor(degmax, 32, 64));
  int dm1 = max(deg - 1, 0);
  const unsigned char* tab = Hf8q + (size_t)q * ((size_t)N * 64);
  const __bf16* ea = eaq + (size_t)q * ((size_t)Mslots * 2);
  f32x4 acc = (f32x4){0.f, 0.f, 0.f, 0.f};
  float den = 0.f;
  for (int i = 0; i < degmax; i += 4) {
    float w[4];
    unsigned int p[4];
#pragma unroll
    for (int u = 0; u < 4; u++) {
      int e = i + u;
      int sl = row0 + min(e, dm1);
      int s = col_s[sl];
      w[u] = (e < deg) ? (float)ea[(size_t)sl * 2 + hh] : 0.f;
      p[u] = *(const unsigned int*)(tab + (size_t)s * 64 + l * 4);
    }
    den += (w[0] + w[1]) + (w[2] + w[3]);
#pragma unroll
    for (int u = 0; u < 4; u++) fma_fp8x4(acc, w[u], p[u]);
  }
  if (active) {
    float rsv = 1.f / den;  // deg >= 1 (self-loop), den > 0
    float4 bv = *(const float4*)(bias + q * 64 + l * 4);
    bf16x4 hb, lb;
#pragma unroll
    for (int j = 0; j < 4; j++) {
      float v = acc[j] * rsv + ((const float*)&bv)[j];
      v = (v > 0.f) ? v : (__expf(v) - 1.f);  // ELU
      hb[j] = (__bf16)v;
      lb[j] = (__bf16)(v - (float)hb[j]);
    }
    *(bf16x4*)(outh + (size_t)node * 256 + q * 64 + l * 4) = hb;
    *(bf16x4*)(outl + (size_t)node * 256 + q * 64 + l * 4) = lb;
  }
}

// ---------------- GAT aggregation, H=1 (layer 3, fp32 out, no ELU) ------
__global__ __launch_bounds__(256) void k_gat_agg1(
    const __bf16* __restrict__ Hh, const int* __restrict__ rowptr,
    const int* __restrict__ col_s, const __bf16* __restrict__ ealpha,
    const float* __restrict__ bias, float* __restrict__ out, int N) {
  int wid = (blockIdx.x * blockDim.x + threadIdx.x) >> 6;
  int lane = threadIdx.x & 63;
  if (wid >= N) return;
  int n = wid;
  int row0 = rowptr[n];
  int deg = rowptr[n + 1] - row0;
  int eo = lane >> 3;
  int cl = lane & 7;
  f32x4 acc = (f32x4){0.f, 0.f, 0.f, 0.f};
  float den = 0.f;
  for (int i = eo; i < deg; i += 8) {
    int slot = row0 + i;
    int src = col_s[slot];
    float w = (float)ealpha[slot];
    den += w;
    bf16x4 hv = *(const bf16x4*)(Hh + (size_t)src * 32 + cl * 4);
#pragma unroll
    for (int j = 0; j < 4; j++) acc[j] += w * (float)hv[j];
  }
#pragma unroll
  for (int off = 8; off < 64; off <<= 1) {
#pragma unroll
    for (int j = 0; j < 4; j++) acc[j] += __shfl_xor(acc[j], off, 64);
    den += __shfl_xor(den, off, 64);
  }
  if (eo == 0) {
    float rsv = 1.f / den;
#pragma unroll
    for (int j = 0; j < 4; j++)
      out[(size_t)n * 32 + cl * 4 + j] = acc[j] * rsv + bias[cl * 4 + j];
  }
}

// ---------------- fused mean-pool + linear ----------------
__global__ __launch_bounds__(256) void k_pool_final(
    const float* __restrict__ h, const int* __restrict__ batch,
    const float* __restrict__ linW, const float* __restrict__ linb,
    float* __restrict__ out, int N) {
  __shared__ float sh[256];
  int g = blockIdx.x;
  int tid = threadIdx.x;
  int grp = tid >> 5, c = tid & 31;
  int lo = 0, hi = N;
  while (lo < hi) { int mid = (lo + hi) >> 1; if (batch[mid] < g) lo = mid + 1; else hi = mid; }
  int start = lo;
  hi = N;
  while (lo < hi) { int mid = (lo + hi) >> 1; if (batch[mid] < g + 1) lo = mid + 1; else hi = mid; }
  int end = lo;
  float acc = 0.f;
  for (int n = start + grp; n < end; n += 8) acc += h[(size_t)n * 32 + c];
  sh[tid] = acc;
  __syncthreads();
  if (tid < 32) {
    float s = 0.f;
#pragma unroll
    for (int j = 0; j < 8; j++) s += sh[j * 32 + tid];
    float v = s * linW[tid];
#pragma unroll
    for (int off = 16; off > 0; off >>= 1) v += __shfl_xor(v, off, 64);
    if (tid == 0) {
      float cnt = (float)(end - start);
      out[g] = v / fmaxf(cnt, 1.f) + linb[0];
    }
  }
}

extern "C" void kernel_launch(void* const* d_in, const int* in_sizes, int n_in,
                              void* d_out, int out_size, void* d_ws, size_t ws_size,
                              hipStream_t stream) {
  const float* x = (const float*)d_in[0];
  const int* ei = (const int*)d_in[1];
  const int* batch = (const int*)d_in[2];
  const float* W1 = (const float*)d_in[3];
  const float* as1 = (const float*)d_in[4];
  const float* ad1 = (const float*)d_in[5];
  const float* b1 = (const float*)d_in[6];
  const float* W2 = (const float*)d_in[7];
  const float* as2 = (const float*)d_in[8];
  const float* ad2 = (const float*)d_in[9];
  const float* b2 = (const float*)d_in[10];
  const float* W3 = (const float*)d_in[11];
  const float* as3 = (const float*)d_in[12];
  const float* ad3 = (const float*)d_in[13];
  const float* b3 = (const float*)d_in[14];
  const float* linW = (const float*)d_in[15];
  const float* linb = (const float*)d_in[16];

  const int N = in_sizes[0] / 256;
  const int E = in_sizes[1] / 2;
  const int NUM_GRAPHS = 64;
  float* out = (float*)d_out;

  char* ws = (char*)d_ws;
  size_t off = 0;
  auto alloc = [&](size_t bytes) -> void* {
    void* p = ws + off;
    off += (bytes + 255) & ~(size_t)255;
    return p;
  };
  __bf16* Hh = (__bf16*)alloc((size_t)N * 256 * 2);  // GEMM h out (bf16-hi)
  unsigned char* Hf8 = (unsigned char*)alloc((size_t)N * 256);  // fp8, quartered
  __bf16* Ah = (__bf16*)alloc((size_t)N * 256 * 2);  // GEMM A in (hi)
  __bf16* Al = (__bf16*)alloc((size_t)N * 256 * 2);  //           (lo)
  __bf16* ealpha = (__bf16*)alloc((size_t)(E + N) * 8 * 2);  // eaq / ealpha1
  float* aS = (float*)alloc((size_t)N * 8 * 4);
  float* aD = (float*)alloc((size_t)N * 8 * 4);
  int* deg = (int*)alloc((size_t)N * 4);
  int* rowptr = (int*)alloc((size_t)(N + 1) * 4);
  int* cursor = (int*)alloc((size_t)(N + 1) * 4);
  int2* col2 = (int2*)alloc((size_t)(E + N) * 8);  // packed (src,dst) per slot
  int* col_s = (int*)alloc((size_t)(E + N) * 4);   // src-only copy
  int* blockSums = (int*)alloc(256 * 4);
  int* blockOffs = (int*)alloc(256 * 4);
  __bf16* WT1h = (__bf16*)alloc(256 * 256 * 2);
  __bf16* WT2h = (__bf16*)alloc(256 * 256 * 2);
  __bf16* WT3h = (__bf16*)alloc(32 * 256 * 2);
  // h3agg reuses Ah (GEMM3 already consumed Ah/Al when agg3 writes)
  float* h3agg = (float*)Ah;

  // --- preps: x split + W transposes + CSR build ---
  k_split<<<(N * 64 + 255) / 256, 256, 0, stream>>>(x, Ah, Al, N * 64);
  k_wprep<<<(256 * 256 + 255) / 256, 256, 0, stream>>>(W1, WT1h, 256, 256);
  k_wprep<<<(256 * 256 + 255) / 256, 256, 0, stream>>>(W2, WT2h, 256, 256);
  k_wprep<<<(256 * 32 + 255) / 256, 256, 0, stream>>>(W3, WT3h, 256, 32);
  k_init_deg<<<(N + 255) / 256, 256, 0, stream>>>(deg, N);
  k_count_deg<<<(E + 255) / 256, 256, 0, stream>>>(ei, E, deg);
  const int nb = (N + 256 * SCAN_CH - 1) / (256 * SCAN_CH);  // 49 <= 256
  k_scan_partial<<<nb, 256, 0, stream>>>(deg, blockSums, N);
  k_scan_blocksums<<<1, 256, 0, stream>>>(blockSums, blockOffs, rowptr, nb, N);
  k_scan_final<<<nb, 256, 0, stream>>>(deg, blockOffs, rowptr, cursor, N);
  {
    const int totalItems = E + N;
    const int nch = 256;  // chunks per stripe; grid = 8*256 = 2048 blocks
    const int chunkSz = (totalItems + nch - 1) / nch;
    k_scatter2<<<8 * nch, 256, 0, stream>>>(ei, E, N, cursor, col2, col_s, chunkSz);
  }

  const int aggBlocks = (N + 3) / 4;
  const int chunks16 = (N + 15) / 16;           // 16 nodes per agg8q block
  const int agg8qGrid = 8 * ((chunks16 + 1) / 2);
  const int gemmBlocks = (N + 63) / 64;  // 64 rows/block, full 256-col width
  const int M = E + N;
  const int edgeBlocks = (M + 255) / 256;
  dim3 g3(1, (N + 63) / 64);

  // --- layer 1 ---
  k_gemm_lds<<<gemmBlocks, 256, 0, stream>>>(Ah, Al, WT1h, Hh, Hf8, N, 256);
  k_att<<<(N * 8 + 255) / 256, 256, 0, stream>>>(Hh, as1, ad1, aS, aD, N * 8, 8);
  k_edge_alpha8<<<edgeBlocks, 256, 0, stream>>>(aS, aD, col2, ealpha, M);
  k_gat_agg8q<<<agg8qGrid, 256, 0, stream>>>(Hf8, rowptr, col_s, ealpha, b1,
                                             Ah, Al, N, M);
  // --- layer 2 ---
  k_gemm_lds<<<gemmBlocks, 256, 0, stream>>>(Ah, Al, WT2h, Hh, Hf8, N, 256);
  k_att<<<(N * 8 + 255) / 256, 256, 0, stream>>>(Hh, as2, ad2, aS, aD, N * 8, 8);
  k_edge_alpha8<<<edgeBlocks, 256, 0, stream>>>(aS, aD, col2, ealpha, M);
  k_gat_agg8q<<<agg8qGrid, 256, 0, stream>>>(Hf8, rowptr, col_s, ealpha, b2,
                                             Ah, Al, N, M);
  // --- layer 3 (H=1, bf16 gather) ---
  k_gemm_split<2, 1><<<g3, 256, 0, stream>>>(Ah, Al, WT3h, Hh, N, 256, 32);
  k_att<<<(N + 255) / 256, 256, 0, stream>>>(Hh, as3, ad3, aS, aD, N, 1);
  k_edge_alpha1<<<edgeBlocks, 256, 0, stream>>>(aS, aD, col2, ealpha, M);
  k_gat_agg1<<<aggBlocks, 256, 0, stream>>>(Hh, rowptr, col_s, ealpha, b3,
                                            h3agg, N);
  // --- pool + final ---
  k_pool_final<<<NUM_GRAPHS, 256, 0, stream>>>(h3agg, batch, linW, linb, out, N);
}

// Round 4
// 488.466 us; speedup vs baseline: 1.2625x; 1.1820x over previous
//
#include <hip/hip_runtime.h>
#include <hip/hip_fp8.h>
#include <math.h>

// ---------------------------------------------------------------------------
// GATClassifier on MI355X.
//   1. CSR build over dst (histogram -> 3-phase scan -> dst-STRIPED scatter:
//      stripe = bid&7 so all writers of a col2 line / cursor[d] land on one
//      XCD; (src,dst) packed int2 + src-only col_s. R15: old scatter wrote
//      84MB HBM for 6.8MB payload (cross-XCD line ping-pong).
//   2. Per layer: MFMA GEMM h = bf16(A) @ bf16(B) — R18: A-lo term DROPPED
//      (R14's error budget: fp8-gather h-err ~2.4e-2 >> bf16-operand err
//      ~1.6e-3; A-bf16 == B-bf16 magnitude). Halves MFMA count (16/k-step),
//      A-bytes, LDS. LDS-staged A, double-buffered, 1 barrier/k-step,
//      64 rows/block. h stored bf16 + flat fp8 copy; agg writes bf16 only.
//      agg8 = R15 shape: wave per node, 64 lanes x 4B contiguous 256B/edge
//      gather, 4-deep unroll, per-lane den. (R16/R17 quartered-L2 shapes cut
//      fetch 96->55MB but regressed dur 2x: 16-lane groups double per-edge
//      instruction cost — shape beats residency for this pattern.)
//   3. Fused mean-pool + 32->1 linear (batch sorted -> binary search)
// History: R2 pool 383. R3 SGEMM 158x2. R4 agg 155x2. R5 gemm 140x2. R6 agg
// 131x2. R7 scan 111. R8 agg 87x2. R9 gemm 89x2. R10 agg 80x2. R11 agg 71x2.
// R12 gemm 57x2. R13 32-row dbuf REGRESSED. R14 64-row dbuf + drop Bl (512).
// R15 striped int2 scatter (506; agg8 46.5x2, 3.2TB/s fabric-bound).
// R16 quartered agg REGRESSED (102x2). R17 requartered REGRESSED (83x2).
// R18 revert agg to R15 shape + drop Al everywhere.
// NOTE: edge_index / batch are int32.
// ---------------------------------------------------------------------------

typedef __attribute__((ext_vector_type(8))) __bf16 bf16x8;
typedef __attribute__((ext_vector_type(4))) __bf16 bf16x4;
typedef __attribute__((ext_vector_type(4))) float f32x4;
typedef __attribute__((ext_vector_type(2))) float f32x2;

#define SCAN_CH 4  // elements per thread in the device-wide scan

__device__ inline unsigned char f32_to_fp8(float f) {
  __hip_fp8_e4m3 v(f);
  return (unsigned char)v.__x;
}
__device__ inline float fp8_to_f32(unsigned char u) {
  __hip_fp8_e4m3 v;
  v.__x = (__hip_fp8_storage_t)u;
  return (float)v;
}

// Decode 4 packed fp8-e4m3 bytes -> 4 floats, accumulate w * val into acc.
__device__ inline void fma_fp8x4(f32x4& acc, float w, unsigned int packed) {
#if defined(__has_builtin) && __has_builtin(__builtin_amdgcn_cvt_pk_f32_fp8)
  f32x2 lo = __builtin_amdgcn_cvt_pk_f32_fp8((int)packed, false);  // bytes 0,1
  f32x2 hi = __builtin_amdgcn_cvt_pk_f32_fp8((int)packed, true);   // bytes 2,3
  acc[0] += w * lo[0];
  acc[1] += w * lo[1];
  acc[2] += w * hi[0];
  acc[3] += w * hi[1];
#else
  acc[0] += w * fp8_to_f32((unsigned char)(packed & 0xff));
  acc[1] += w * fp8_to_f32((unsigned char)((packed >> 8) & 0xff));
  acc[2] += w * fp8_to_f32((unsigned char)((packed >> 16) & 0xff));
  acc[3] += w * fp8_to_f32((unsigned char)(packed >> 24));
#endif
}

// ---------------- CSR build ----------------
__global__ __launch_bounds__(256) void k_init_deg(int* deg, int N) {
  int n = blockIdx.x * 256 + threadIdx.x;
  if (n < N) deg[n] = 1;  // self-loop
}

__global__ __launch_bounds__(256) void k_count_deg(const int* __restrict__ ei,
                                                   int E, int* deg) {
  int e = blockIdx.x * 256 + threadIdx.x;
  if (e < E) atomicAdd(&deg[ei[E + e]], 1);
}

// --- 3-phase exclusive scan (R8: old single-block scan was 111us on 1 CU) ---
__global__ __launch_bounds__(256) void k_scan_partial(const int* __restrict__ deg,
                                                      int* __restrict__ blockSums,
                                                      int N) {
  __shared__ int sh[256];
  int t = threadIdx.x, b = blockIdx.x;
  int base = (b * 256 + t) * SCAN_CH;
  int s = 0;
#pragma unroll
  for (int j = 0; j < SCAN_CH; j++) {
    int idx = base + j;
    if (idx < N) s += deg[idx];
  }
  sh[t] = s;
  __syncthreads();
  for (int off = 128; off > 0; off >>= 1) {
    if (t < off) sh[t] += sh[t + off];
    __syncthreads();
  }
  if (t == 0) blockSums[b] = sh[0];
}

__global__ __launch_bounds__(256) void k_scan_blocksums(
    const int* __restrict__ blockSums, int* __restrict__ blockOffs,
    int* __restrict__ rowptr, int nb, int N) {
  __shared__ int sh[256];
  int t = threadIdx.x;
  int v = (t < nb) ? blockSums[t] : 0;
  sh[t] = v;
  __syncthreads();
  for (int off = 1; off < 256; off <<= 1) {
    int u = (t >= off) ? sh[t - off] : 0;
    __syncthreads();
    sh[t] += u;
    __syncthreads();
  }
  if (t < nb) blockOffs[t] = sh[t] - v;  // exclusive
  if (t == nb - 1) rowptr[N] = sh[t];    // total
}

__global__ __launch_bounds__(256) void k_scan_final(const int* __restrict__ deg,
                                                    const int* __restrict__ blockOffs,
                                                    int* __restrict__ rowptr,
                                                    int* __restrict__ cursor, int N) {
  __shared__ int sh[256];
  int t = threadIdx.x, b = blockIdx.x;
  int base = (b * 256 + t) * SCAN_CH;
  int vals[SCAN_CH];
  int s = 0;
#pragma unroll
  for (int j = 0; j < SCAN_CH; j++) {
    int idx = base + j;
    vals[j] = (idx < N) ? deg[idx] : 0;
    s += vals[j];
  }
  sh[t] = s;
  __syncthreads();
  for (int off = 1; off < 256; off <<= 1) {
    int u = (t >= off) ? sh[t - off] : 0;
    __syncthreads();
    sh[t] += u;
    __syncthreads();
  }
  int run = blockOffs[b] + sh[t] - s;  // exclusive prefix for this thread
#pragma unroll
  for (int j = 0; j < SCAN_CH; j++) {
    int idx = base + j;
    if (idx < N) {
      rowptr[idx] = run;
      cursor[idx] = run;
      run += vals[j];
    }
  }
}

// dst-striped scatter (R15). Grid = 8 stripes x nch chunks; stripe = bid&7
// (matches the HW's round-robin block->XCD mapping, so all writes/atomics
// for a given dst land on one XCD's L2 — heuristic only, never a
// correctness dependence). Packed int2 store + src-only col_s.
__global__ __launch_bounds__(256) void k_scatter2(const int* __restrict__ ei,
                                                  int E, int N, int* cursor,
                                                  int2* __restrict__ col2,
                                                  int* __restrict__ col_s,
                                                  int chunkSz) {
  int stripe = blockIdx.x & 7;
  int chunk = blockIdx.x >> 3;
  int lo = (int)(((long long)N * stripe) >> 3);
  int hi = (int)(((long long)N * (stripe + 1)) >> 3);
  int base = chunk * chunkSz;
  int end = base + chunkSz;
  int total = E + N;
  if (end > total) end = total;
  for (int i = base + threadIdx.x; i < end; i += 256) {
    int d = (i < E) ? ei[E + i] : (i - E);
    if (d < lo || d >= hi) continue;
    int s = (i < E) ? ei[i] : d;
    int pos = atomicAdd(&cursor[d], 1);
    col2[pos] = make_int2(s, d);
    col_s[pos] = s;
  }
}

// ---------------- cast prep (R18: plain bf16, no lo term) ----------------
__global__ __launch_bounds__(256) void k_cast(const float* __restrict__ in,
                                              __bf16* __restrict__ oh, int n4) {
  int i = blockIdx.x * 256 + threadIdx.x;
  if (i >= n4) return;
  float4 v = ((const float4*)in)[i];
  bf16x4 h;
  h[0] = (__bf16)v.x;
  h[1] = (__bf16)v.y;
  h[2] = (__bf16)v.z;
  h[3] = (__bf16)v.w;
  ((bf16x4*)oh)[i] = h;
}

// W [K][Nc] fp32 -> WT [Nc][K] plain bf16 (R14: B-lo dropped — B-bytes were
// the binding GEMM resource; h-error 1.6e-3 washes to ~2e-5 at output).
__global__ __launch_bounds__(256) void k_wprep(const float* __restrict__ W,
                                               __bf16* __restrict__ WTh,
                                               int K, int Nc) {
  int i = blockIdx.x * 256 + threadIdx.x;  // i = n*K + k
  if (i >= K * Nc) return;
  int n = i / K, k = i - n * K;
  WTh[i] = (__bf16)W[k * Nc + n];
}

// ---------------- LDS-shared MFMA GEMM (layers 1/2, R18) -----------------
// C = Ah @ Bh, both plain bf16. Block = 64 rows x 256 cols. A-tile (64x32,
// 4KB) double-buffered in LDS, 1-step prefetch, 1 barrier/k-step.
// Per k-step per wave: 4 B-loads + 16 MFMAs.
// mfma_f32_16x16x32_bf16 (m89-verified): A: m=lane&15,k=quad*8+j;
// B: n=lane&15,k=quad*8+j (from WT); C/D: row=quad*4+reg, col=lane&15.
__global__ __launch_bounds__(256) void k_gemm_lds(
    const __bf16* __restrict__ Ah, const __bf16* __restrict__ BTh,
    __bf16* __restrict__ Ch, unsigned char* __restrict__ Cf8, int M, int K) {
  constexpr int NcFull = 256;
  __shared__ __bf16 sAh[2][2048];  // [buf][(mt*4+kq)*16+l16][8]
  int tid = threadIdx.x;
  int lane = tid & 63, wave = tid >> 6;
  int quad = lane >> 4, l16 = lane & 15;
  int m0 = blockIdx.x * 64;
  int col0 = wave * 64;
  // staging map: thread t -> row sr = t>>2 (0..63), k-quad skq = t&3
  int sr = tid >> 2, skq = tid & 3;
  int slot8 = (((sr >> 4) * 4 + skq) * 16 + (sr & 15)) * 8;
  int arow = min(m0 + sr, M - 1);  // clamp: rows >= M never stored
  const __bf16* agh = Ah + (size_t)arow * K + skq * 8;
  const __bf16* brh = BTh + (size_t)(col0 + l16) * K + quad * 8;
  f32x4 acc[4][4];  // [mt][nt]
#pragma unroll
  for (int mt = 0; mt < 4; mt++)
#pragma unroll
    for (int t = 0; t < 4; t++) acc[mt][t] = (f32x4){0.f, 0.f, 0.f, 0.f};
  // prologue: stage k0=0 into buf0
  *(bf16x8*)(sAh[0] + slot8) = *(const bf16x8*)agh;
  __syncthreads();
  int buf = 0;
  for (int k0 = 0; k0 < K; k0 += 32, buf ^= 1) {
    bool more = (k0 + 32 < K);
    bf16x8 gh;
    if (more) {  // prefetch A(k+1); has the whole compute phase to land
      gh = *(const bf16x8*)(agh + k0 + 32);
    }
    bf16x8 b_h[4];
#pragma unroll
    for (int t = 0; t < 4; t++)
      b_h[t] = *(const bf16x8*)(brh + (size_t)t * 16 * K + k0);
    const __bf16* rh = sAh[buf];
    bf16x8 a_h[4];
#pragma unroll
    for (int mt = 0; mt < 4; mt++) {
      int fi = ((mt * 4 + quad) * 16 + l16) * 8;
      a_h[mt] = *(const bf16x8*)(rh + fi);
    }
#pragma unroll
    for (int t = 0; t < 4; t++) {
#pragma unroll
      for (int mt = 0; mt < 4; mt++) {
        acc[mt][t] = __builtin_amdgcn_mfma_f32_16x16x32_bf16(a_h[mt], b_h[t], acc[mt][t], 0, 0, 0);
      }
    }
    // write A(k+1) to the alternate buffer (its readers were fenced by the
    // previous barrier); single barrier per step.
    if (more) {
      *(bf16x8*)(sAh[buf ^ 1] + slot8) = gh;
    }
    __syncthreads();
  }
#pragma unroll
  for (int mt = 0; mt < 4; mt++) {
#pragma unroll
    for (int t = 0; t < 4; t++) {
#pragma unroll
      for (int r = 0; r < 4; r++) {
        int m = m0 + mt * 16 + quad * 4 + r;
        if (m < M) {
          size_t o = (size_t)m * NcFull + col0 + t * 16 + l16;
          Ch[o] = (__bf16)acc[mt][t][r];
          Cf8[o] = f32_to_fp8(acc[mt][t][r]);
        }
      }
    }
  }
}

// ---------------- MFMA GEMM, no-LDS (layer 3): Ah @ Bh ------------------
template <int NT, int MT>
__global__ __launch_bounds__(256) void k_gemm_split(
    const __bf16* __restrict__ Ah, const __bf16* __restrict__ BTh,
    __bf16* __restrict__ Ch, int M, int K, int NcFull) {
  int lane = threadIdx.x & 63;
  int wave = threadIdx.x >> 6;
  int quad = lane >> 4;
  int l16 = lane & 15;
  int m0 = blockIdx.y * (64 * MT) + wave * (16 * MT);
  int col0 = blockIdx.x * (NT * 16);
  const __bf16* arh[MT];
#pragma unroll
  for (int mt = 0; mt < MT; mt++) {
    int am = min(m0 + mt * 16 + l16, M - 1);
    arh[mt] = Ah + (size_t)am * K + quad * 8;
  }
  const __bf16* brh = BTh + (size_t)(col0 + l16) * K + quad * 8;
  f32x4 acc[MT][NT];
#pragma unroll
  for (int mt = 0; mt < MT; mt++)
#pragma unroll
    for (int t = 0; t < NT; t++) acc[mt][t] = (f32x4){0.f, 0.f, 0.f, 0.f};
  for (int k0 = 0; k0 < K; k0 += 32) {
    bf16x8 a_h[MT], b_h[NT];
#pragma unroll
    for (int mt = 0; mt < MT; mt++) {
      a_h[mt] = *(const bf16x8*)(arh[mt] + k0);
    }
#pragma unroll
    for (int t = 0; t < NT; t++)
      b_h[t] = *(const bf16x8*)(brh + (size_t)t * 16 * K + k0);
#pragma unroll
    for (int t = 0; t < NT; t++) {
#pragma unroll
      for (int mt = 0; mt < MT; mt++) {
        acc[mt][t] = __builtin_amdgcn_mfma_f32_16x16x32_bf16(a_h[mt], b_h[t], acc[mt][t], 0, 0, 0);
      }
    }
  }
#pragma unroll
  for (int mt = 0; mt < MT; mt++) {
#pragma unroll
    for (int t = 0; t < NT; t++) {
#pragma unroll
      for (int r = 0; r < 4; r++) {
        int m = m0 + mt * 16 + quad * 4 + r;
        if (m < M)
          Ch[(size_t)m * NcFull + col0 + t * 16 + l16] = (__bf16)acc[mt][t][r];
      }
    }
  }
}

// ---------------- attention dots (bf16) ----------------
__global__ __launch_bounds__(256) void k_att(const __bf16* __restrict__ Hh,
                                             const float* __restrict__ attS,
                                             const float* __restrict__ attD,
                                             float* __restrict__ aS,
                                             float* __restrict__ aD, int NH, int H) {
  int idx = blockIdx.x * 256 + threadIdx.x;
  if (idx >= NH) return;
  int h = idx % H;
  const bf16x8* hv = (const bf16x8*)(Hh + (size_t)idx * 32);
  const float* sv = attS + h * 32;
  const float* dv = attD + h * 32;
  float ss = 0.f, dd = 0.f;
#pragma unroll
  for (int k = 0; k < 4; k++) {
    bf16x8 a = hv[k];
#pragma unroll
    for (int j = 0; j < 8; j++) {
      float v = (float)a[j];
      ss += v * sv[k * 8 + j];
      dd += v * dv[k * 8 + j];
    }
  }
  aS[idx] = ss;
  aD[idx] = dd;
}

// ---------------- dense edge-parallel alpha (R12) ----------------
__global__ __launch_bounds__(256) void k_edge_alpha8(
    const float* __restrict__ aS, const float* __restrict__ aD,
    const int2* __restrict__ col2,
    __bf16* __restrict__ ealpha, int M) {
  int e = blockIdx.x * 256 + threadIdx.x;
  if (e >= M) return;
  int2 sd = col2[e];
  const float* ap = aS + (size_t)sd.x * 8;
  const float* dp = aD + (size_t)sd.y * 8;
  bf16x8 ev;
#pragma unroll
  for (int h = 0; h < 8; h++) {
    float x = ap[h] + dp[h];
    x = (x > 0.f) ? x : 0.2f * x;
    ev[h] = (__bf16)__expf(x);
  }
  *(bf16x8*)(ealpha + (size_t)e * 8) = ev;
}

__global__ __launch_bounds__(256) void k_edge_alpha1(
    const float* __restrict__ aS, const float* __restrict__ aD,
    const int2* __restrict__ col2,
    __bf16* __restrict__ ealpha, int M) {
  int e = blockIdx.x * 256 + threadIdx.x;
  if (e >= M) return;
  int2 sd = col2[e];
  float x = aS[sd.x] + aD[sd.y];
  x = (x > 0.f) ? x : 0.2f * x;
  ealpha[e] = (__bf16)__expf(x);
}

// ---------------- GAT aggregation, H=8 (R15 shape, R18 bf16-only out) ----
// wave per node, 64 lanes x 4B = contiguous 256B/edge gather, 4-deep
// unroll, per-lane den (no shuffles). Writes bf16 h only (no lo term).
__global__ __launch_bounds__(256) void k_gat_agg8(
    const unsigned char* __restrict__ Hf8, const int* __restrict__ rowptr,
    const int* __restrict__ col_s, const __bf16* __restrict__ ealpha,
    const float* __restrict__ bias, __bf16* __restrict__ outh, int N) {
  int wid = (blockIdx.x * blockDim.x + threadIdx.x) >> 6;
  int lane = threadIdx.x & 63;
  if (wid >= N) return;
  int n = wid;
  int row0 = rowptr[n];
  int deg = rowptr[n + 1] - row0;
  int head = lane >> 3;

  f32x4 acc = (f32x4){0.f, 0.f, 0.f, 0.f};
  float den = 0.f;
  const __bf16* ea = ealpha;
  int i = 0;
  for (; i + 3 < deg; i += 4) {
    int sl = row0 + i;
    int s0 = col_s[sl + 0];
    int s1 = col_s[sl + 1];
    int s2 = col_s[sl + 2];
    int s3 = col_s[sl + 3];
    float w0 = (float)ea[(size_t)(sl + 0) * 8 + head];
    float w1 = (float)ea[(size_t)(sl + 1) * 8 + head];
    float w2 = (float)ea[(size_t)(sl + 2) * 8 + head];
    float w3 = (float)ea[(size_t)(sl + 3) * 8 + head];
    unsigned int p0 = *(const unsigned int*)(Hf8 + (size_t)s0 * 256 + lane * 4);
    unsigned int p1 = *(const unsigned int*)(Hf8 + (size_t)s1 * 256 + lane * 4);
    unsigned int p2 = *(const unsigned int*)(Hf8 + (size_t)s2 * 256 + lane * 4);
    unsigned int p3 = *(const unsigned int*)(Hf8 + (size_t)s3 * 256 + lane * 4);
    den += w0 + w1 + w2 + w3;
    fma_fp8x4(acc, w0, p0);
    fma_fp8x4(acc, w1, p1);
    fma_fp8x4(acc, w2, p2);
    fma_fp8x4(acc, w3, p3);
  }
  for (; i < deg; i++) {
    int sl = row0 + i;
    int s0 = col_s[sl];
    float w0 = (float)ea[(size_t)sl * 8 + head];
    unsigned int p0 = *(const unsigned int*)(Hf8 + (size_t)s0 * 256 + lane * 4);
    den += w0;
    fma_fp8x4(acc, w0, p0);
  }
  float rsv = 1.f / den;  // deg >= 1 (self-loop), den > 0
  float4 bv = *(const float4*)(bias + lane * 4);
  bf16x4 hb;
#pragma unroll
  for (int j = 0; j < 4; j++) {
    float v = acc[j] * rsv + ((const float*)&bv)[j];
    v = (v > 0.f) ? v : (__expf(v) - 1.f);  // ELU
    hb[j] = (__bf16)v;
  }
  *(bf16x4*)(outh + (size_t)n * 256 + lane * 4) = hb;
}

// ---------------- GAT aggregation, H=1 (layer 3, fp32 out, no ELU) ------
__global__ __launch_bounds__(256) void k_gat_agg1(
    const __bf16* __restrict__ Hh, const int* __restrict__ rowptr,
    const int* __restrict__ col_s, const __bf16* __restrict__ ealpha,
    const float* __restrict__ bias, float* __restrict__ out, int N) {
  int wid = (blockIdx.x * blockDim.x + threadIdx.x) >> 6;
  int lane = threadIdx.x & 63;
  if (wid >= N) return;
  int n = wid;
  int row0 = rowptr[n];
  int deg = rowptr[n + 1] - row0;
  int eo = lane >> 3;
  int cl = lane & 7;
  f32x4 acc = (f32x4){0.f, 0.f, 0.f, 0.f};
  float den = 0.f;
  for (int i = eo; i < deg; i += 8) {
    int slot = row0 + i;
    int src = col_s[slot];
    float w = (float)ealpha[slot];
    den += w;
    bf16x4 hv = *(const bf16x4*)(Hh + (size_t)src * 32 + cl * 4);
#pragma unroll
    for (int j = 0; j < 4; j++) acc[j] += w * (float)hv[j];
  }
#pragma unroll
  for (int off = 8; off < 64; off <<= 1) {
#pragma unroll
    for (int j = 0; j < 4; j++) acc[j] += __shfl_xor(acc[j], off, 64);
    den += __shfl_xor(den, off, 64);
  }
  if (eo == 0) {
    float rsv = 1.f / den;
#pragma unroll
    for (int j = 0; j < 4; j++)
      out[(size_t)n * 32 + cl * 4 + j] = acc[j] * rsv + bias[cl * 4 + j];
  }
}

// ---------------- fused mean-pool + linear ----------------
__global__ __launch_bounds__(256) void k_pool_final(
    const float* __restrict__ h, const int* __restrict__ batch,
    const float* __restrict__ linW, const float* __restrict__ linb,
    float* __restrict__ out, int N) {
  __shared__ float sh[256];
  int g = blockIdx.x;
  int tid = threadIdx.x;
  int grp = tid >> 5, c = tid & 31;
  int lo = 0, hi = N;
  while (lo < hi) { int mid = (lo + hi) >> 1; if (batch[mid] < g) lo = mid + 1; else hi = mid; }
  int start = lo;
  hi = N;
  while (lo < hi) { int mid = (lo + hi) >> 1; if (batch[mid] < g + 1) lo = mid + 1; else hi = mid; }
  int end = lo;
  float acc = 0.f;
  for (int n = start + grp; n < end; n += 8) acc += h[(size_t)n * 32 + c];
  sh[tid] = acc;
  __syncthreads();
  if (tid < 32) {
    float s = 0.f;
#pragma unroll
    for (int j = 0; j < 8; j++) s += sh[j * 32 + tid];
    float v = s * linW[tid];
#pragma unroll
    for (int off = 16; off > 0; off >>= 1) v += __shfl_xor(v, off, 64);
    if (tid == 0) {
      float cnt = (float)(end - start);
      out[g] = v / fmaxf(cnt, 1.f) + linb[0];
    }
  }
}

extern "C" void kernel_launch(void* const* d_in, const int* in_sizes, int n_in,
                              void* d_out, int out_size, void* d_ws, size_t ws_size,
                              hipStream_t stream) {
  const float* x = (const float*)d_in[0];
  const int* ei = (const int*)d_in[1];
  const int* batch = (const int*)d_in[2];
  const float* W1 = (const float*)d_in[3];
  const float* as1 = (const float*)d_in[4];
  const float* ad1 = (const float*)d_in[5];
  const float* b1 = (const float*)d_in[6];
  const float* W2 = (const float*)d_in[7];
  const float* as2 = (const float*)d_in[8];
  const float* ad2 = (const float*)d_in[9];
  const float* b2 = (const float*)d_in[10];
  const float* W3 = (const float*)d_in[11];
  const float* as3 = (const float*)d_in[12];
  const float* ad3 = (const float*)d_in[13];
  const float* b3 = (const float*)d_in[14];
  const float* linW = (const float*)d_in[15];
  const float* linb = (const float*)d_in[16];

  const int N = in_sizes[0] / 256;
  const int E = in_sizes[1] / 2;
  const int NUM_GRAPHS = 64;
  float* out = (float*)d_out;

  char* ws = (char*)d_ws;
  size_t off = 0;
  auto alloc = [&](size_t bytes) -> void* {
    void* p = ws + off;
    off += (bytes + 255) & ~(size_t)255;
    return p;
  };
  __bf16* Hh = (__bf16*)alloc((size_t)N * 256 * 2);  // GEMM h out (bf16)
  unsigned char* Hf8 = (unsigned char*)alloc((size_t)N * 256);  // fp8 copy
  __bf16* Ah = (__bf16*)alloc((size_t)N * 256 * 2);  // GEMM A in (bf16)
  __bf16* ealpha = (__bf16*)alloc((size_t)(E + N) * 8 * 2);  // per-edge exps
  float* aS = (float*)alloc((size_t)N * 8 * 4);
  float* aD = (float*)alloc((size_t)N * 8 * 4);
  int* deg = (int*)alloc((size_t)N * 4);
  int* rowptr = (int*)alloc((size_t)(N + 1) * 4);
  int* cursor = (int*)alloc((size_t)(N + 1) * 4);
  int2* col2 = (int2*)alloc((size_t)(E + N) * 8);  // packed (src,dst) per slot
  int* col_s = (int*)alloc((size_t)(E + N) * 4);   // src-only copy
  int* blockSums = (int*)alloc(256 * 4);
  int* blockOffs = (int*)alloc(256 * 4);
  __bf16* WT1h = (__bf16*)alloc(256 * 256 * 2);
  __bf16* WT2h = (__bf16*)alloc(256 * 256 * 2);
  __bf16* WT3h = (__bf16*)alloc(32 * 256 * 2);
  // h3agg reuses Ah (GEMM3 already consumed Ah when agg3 writes)
  float* h3agg = (float*)Ah;

  // --- preps: x cast + W transposes + CSR build ---
  k_cast<<<(N * 64 + 255) / 256, 256, 0, stream>>>(x, Ah, N * 64);
  k_wprep<<<(256 * 256 + 255) / 256, 256, 0, stream>>>(W1, WT1h, 256, 256);
  k_wprep<<<(256 * 256 + 255) / 256, 256, 0, stream>>>(W2, WT2h, 256, 256);
  k_wprep<<<(256 * 32 + 255) / 256, 256, 0, stream>>>(W3, WT3h, 256, 32);
  k_init_deg<<<(N + 255) / 256, 256, 0, stream>>>(deg, N);
  k_count_deg<<<(E + 255) / 256, 256, 0, stream>>>(ei, E, deg);
  const int nb = (N + 256 * SCAN_CH - 1) / (256 * SCAN_CH);  // 49 <= 256
  k_scan_partial<<<nb, 256, 0, stream>>>(deg, blockSums, N);
  k_scan_blocksums<<<1, 256, 0, stream>>>(blockSums, blockOffs, rowptr, nb, N);
  k_scan_final<<<nb, 256, 0, stream>>>(deg, blockOffs, rowptr, cursor, N);
  {
    const int totalItems = E + N;
    const int nch = 256;  // chunks per stripe; grid = 8*256 = 2048 blocks
    const int chunkSz = (totalItems + nch - 1) / nch;
    k_scatter2<<<8 * nch, 256, 0, stream>>>(ei, E, N, cursor, col2, col_s, chunkSz);
  }

  const int aggBlocks = (N + 3) / 4;
  const int gemmBlocks = (N + 63) / 64;  // 64 rows/block, full 256-col width
  const int M = E + N;
  const int edgeBlocks = (M + 255) / 256;
  dim3 g3(1, (N + 63) / 64);

  // --- layer 1 ---
  k_gemm_lds<<<gemmBlocks, 256, 0, stream>>>(Ah, WT1h, Hh, Hf8, N, 256);
  k_att<<<(N * 8 + 255) / 256, 256, 0, stream>>>(Hh, as1, ad1, aS, aD, N * 8, 8);
  k_edge_alpha8<<<edgeBlocks, 256, 0, stream>>>(aS, aD, col2, ealpha, M);
  k_gat_agg8<<<aggBlocks, 256, 0, stream>>>(Hf8, rowptr, col_s, ealpha, b1,
                                            Ah, N);
  // --- layer 2 ---
  k_gemm_lds<<<gemmBlocks, 256, 0, stream>>>(Ah, WT2h, Hh, Hf8, N, 256);
  k_att<<<(N * 8 + 255) / 256, 256, 0, stream>>>(Hh, as2, ad2, aS, aD, N * 8, 8);
  k_edge_alpha8<<<edgeBlocks, 256, 0, stream>>>(aS, aD, col2, ealpha, M);
  k_gat_agg8<<<aggBlocks, 256, 0, stream>>>(Hf8, rowptr, col_s, ealpha, b2,
                                            Ah, N);
  // --- layer 3 (H=1, bf16 gather) ---
  k_gemm_split<2, 1><<<g3, 256, 0, stream>>>(Ah, WT3h, Hh, N, 256, 32);
  k_att<<<(N + 255) / 256, 256, 0, stream>>>(Hh, as3, ad3, aS, aD, N, 1);
  k_edge_alpha1<<<edgeBlocks, 256, 0, stream>>>(aS, aD, col2, ealpha, M);
  k_gat_agg1<<<aggBlocks, 256, 0, stream>>>(Hh, rowptr, col_s, ealpha, b3,
                                            h3agg, N);
  // --- pool + final ---
  k_pool_final<<<NUM_GRAPHS, 256, 0, stream>>>(h3agg, batch, linW, linb, out, N);
}

// Round 5
// 482.994 us; speedup vs baseline: 1.2768x; 1.0113x over previous
//
#include <hip/hip_runtime.h>
#include <hip/hip_fp8.h>
#include <math.h>

// ---------------------------------------------------------------------------
// GATClassifier on MI355X.
//   1. CSR build over dst (histogram -> 3-phase scan -> dst-STRIPED scatter:
//      stripe = bid&7 so all writers of a col2 line / cursor[d] land on one
//      XCD; (src,dst) packed int2 + src-only col_s. R15: old scatter wrote
//      84MB HBM for 6.8MB payload (cross-XCD line ping-pong).
//   2. Per layer: MFMA GEMM h = bf16(A) @ bf16(B) (R18: split-lo terms
//      dropped; fp8-gather error term dominates, absmax 2.4e-4 passes).
//      R19: GEMM restructured — stage the ENTIRE 64x256 A-strip (32KB,
//      fragment-ordered) with ONE barrier, then a barrier-free k-loop.
//      R18's 2-barrier/k-step dbuf was latency-serialized: dur invariant
//      to halving MFMAs (56us, MfmaUtil 4%, VALUBusy 10%, Occ 24% — all
//      pipes idle). h stored bf16 + flat fp8 copy.
//      agg8 = R15 shape: wave per node, 64 lanes x 4B contiguous 256B/edge
//      gather, 4-deep unroll, per-lane den. (R16/R17 quartered-L2 shapes cut
//      fetch 96->55MB but regressed dur 2x: shape beats residency here.)
//   3. Fused mean-pool + 32->1 linear (batch sorted -> binary search)
// History: R2 pool 383. R3 SGEMM 158x2. R4 agg 155x2. R5 gemm 140x2. R6 agg
// 131x2. R7 scan 111. R8 agg 87x2. R9 gemm 89x2. R10 agg 80x2. R11 agg 71x2.
// R12 gemm 57x2. R13 32-row dbuf REGRESSED. R14 64-row dbuf + drop Bl (512).
// R15 striped int2 scatter (506; agg8 46.5x2). R16 quartered agg REGRESSED
// (102x2). R17 requartered REGRESSED (83x2). R18 drop lo-terms (488;
// gemm 56x2 latency-bound). R19 single-barrier full-A-stage GEMM.
// NOTE: edge_index / batch are int32.
// ---------------------------------------------------------------------------

typedef __attribute__((ext_vector_type(8))) __bf16 bf16x8;
typedef __attribute__((ext_vector_type(4))) __bf16 bf16x4;
typedef __attribute__((ext_vector_type(4))) float f32x4;
typedef __attribute__((ext_vector_type(2))) float f32x2;

#define SCAN_CH 4  // elements per thread in the device-wide scan

__device__ inline unsigned char f32_to_fp8(float f) {
  __hip_fp8_e4m3 v(f);
  return (unsigned char)v.__x;
}
__device__ inline float fp8_to_f32(unsigned char u) {
  __hip_fp8_e4m3 v;
  v.__x = (__hip_fp8_storage_t)u;
  return (float)v;
}

// Decode 4 packed fp8-e4m3 bytes -> 4 floats, accumulate w * val into acc.
__device__ inline void fma_fp8x4(f32x4& acc, float w, unsigned int packed) {
#if defined(__has_builtin) && __has_builtin(__builtin_amdgcn_cvt_pk_f32_fp8)
  f32x2 lo = __builtin_amdgcn_cvt_pk_f32_fp8((int)packed, false);  // bytes 0,1
  f32x2 hi = __builtin_amdgcn_cvt_pk_f32_fp8((int)packed, true);   // bytes 2,3
  acc[0] += w * lo[0];
  acc[1] += w * lo[1];
  acc[2] += w * hi[0];
  acc[3] += w * hi[1];
#else
  acc[0] += w * fp8_to_f32((unsigned char)(packed & 0xff));
  acc[1] += w * fp8_to_f32((unsigned char)((packed >> 8) & 0xff));
  acc[2] += w * fp8_to_f32((unsigned char)((packed >> 16) & 0xff));
  acc[3] += w * fp8_to_f32((unsigned char)(packed >> 24));
#endif
}

// ---------------- CSR build ----------------
__global__ __launch_bounds__(256) void k_init_deg(int* deg, int N) {
  int n = blockIdx.x * 256 + threadIdx.x;
  if (n < N) deg[n] = 1;  // self-loop
}

__global__ __launch_bounds__(256) void k_count_deg(const int* __restrict__ ei,
                                                   int E, int* deg) {
  int e = blockIdx.x * 256 + threadIdx.x;
  if (e < E) atomicAdd(&deg[ei[E + e]], 1);
}

// --- 3-phase exclusive scan (R8: old single-block scan was 111us on 1 CU) ---
__global__ __launch_bounds__(256) void k_scan_partial(const int* __restrict__ deg,
                                                      int* __restrict__ blockSums,
                                                      int N) {
  __shared__ int sh[256];
  int t = threadIdx.x, b = blockIdx.x;
  int base = (b * 256 + t) * SCAN_CH;
  int s = 0;
#pragma unroll
  for (int j = 0; j < SCAN_CH; j++) {
    int idx = base + j;
    if (idx < N) s += deg[idx];
  }
  sh[t] = s;
  __syncthreads();
  for (int off = 128; off > 0; off >>= 1) {
    if (t < off) sh[t] += sh[t + off];
    __syncthreads();
  }
  if (t == 0) blockSums[b] = sh[0];
}

__global__ __launch_bounds__(256) void k_scan_blocksums(
    const int* __restrict__ blockSums, int* __restrict__ blockOffs,
    int* __restrict__ rowptr, int nb, int N) {
  __shared__ int sh[256];
  int t = threadIdx.x;
  int v = (t < nb) ? blockSums[t] : 0;
  sh[t] = v;
  __syncthreads();
  for (int off = 1; off < 256; off <<= 1) {
    int u = (t >= off) ? sh[t - off] : 0;
    __syncthreads();
    sh[t] += u;
    __syncthreads();
  }
  if (t < nb) blockOffs[t] = sh[t] - v;  // exclusive
  if (t == nb - 1) rowptr[N] = sh[t];    // total
}

__global__ __launch_bounds__(256) void k_scan_final(const int* __restrict__ deg,
                                                    const int* __restrict__ blockOffs,
                                                    int* __restrict__ rowptr,
                                                    int* __restrict__ cursor, int N) {
  __shared__ int sh[256];
  int t = threadIdx.x, b = blockIdx.x;
  int base = (b * 256 + t) * SCAN_CH;
  int vals[SCAN_CH];
  int s = 0;
#pragma unroll
  for (int j = 0; j < SCAN_CH; j++) {
    int idx = base + j;
    vals[j] = (idx < N) ? deg[idx] : 0;
    s += vals[j];
  }
  sh[t] = s;
  __syncthreads();
  for (int off = 1; off < 256; off <<= 1) {
    int u = (t >= off) ? sh[t - off] : 0;
    __syncthreads();
    sh[t] += u;
    __syncthreads();
  }
  int run = blockOffs[b] + sh[t] - s;  // exclusive prefix for this thread
#pragma unroll
  for (int j = 0; j < SCAN_CH; j++) {
    int idx = base + j;
    if (idx < N) {
      rowptr[idx] = run;
      cursor[idx] = run;
      run += vals[j];
    }
  }
}

// dst-striped scatter (R15). Grid = 8 stripes x nch chunks; stripe = bid&7
// (matches the HW's round-robin block->XCD mapping, so all writes/atomics
// for a given dst land on one XCD's L2 — heuristic only, never a
// correctness dependence). Packed int2 store + src-only col_s.
__global__ __launch_bounds__(256) void k_scatter2(const int* __restrict__ ei,
                                                  int E, int N, int* cursor,
                                                  int2* __restrict__ col2,
                                                  int* __restrict__ col_s,
                                                  int chunkSz) {
  int stripe = blockIdx.x & 7;
  int chunk = blockIdx.x >> 3;
  int lo = (int)(((long long)N * stripe) >> 3);
  int hi = (int)(((long long)N * (stripe + 1)) >> 3);
  int base = chunk * chunkSz;
  int end = base + chunkSz;
  int total = E + N;
  if (end > total) end = total;
  for (int i = base + threadIdx.x; i < end; i += 256) {
    int d = (i < E) ? ei[E + i] : (i - E);
    if (d < lo || d >= hi) continue;
    int s = (i < E) ? ei[i] : d;
    int pos = atomicAdd(&cursor[d], 1);
    col2[pos] = make_int2(s, d);
    col_s[pos] = s;
  }
}

// ---------------- cast prep (R18: plain bf16, no lo term) ----------------
__global__ __launch_bounds__(256) void k_cast(const float* __restrict__ in,
                                              __bf16* __restrict__ oh, int n4) {
  int i = blockIdx.x * 256 + threadIdx.x;
  if (i >= n4) return;
  float4 v = ((const float4*)in)[i];
  bf16x4 h;
  h[0] = (__bf16)v.x;
  h[1] = (__bf16)v.y;
  h[2] = (__bf16)v.z;
  h[3] = (__bf16)v.w;
  ((bf16x4*)oh)[i] = h;
}

// W [K][Nc] fp32 -> WT [Nc][K] plain bf16 (R14: B-lo dropped — B-bytes were
// the binding GEMM resource; h-error 1.6e-3 washes to ~2e-5 at output).
__global__ __launch_bounds__(256) void k_wprep(const float* __restrict__ W,
                                               __bf16* __restrict__ WTh,
                                               int K, int Nc) {
  int i = blockIdx.x * 256 + threadIdx.x;  // i = n*K + k
  if (i >= K * Nc) return;
  int n = i / K, k = i - n * K;
  WTh[i] = (__bf16)W[k * Nc + n];
}

// ---------------- LDS-shared MFMA GEMM (layers 1/2, R19) -----------------
// C = Ah @ Bh, plain bf16. Block = 64 rows x 256 cols (782 blocks, 4 waves).
// R19: stage the WHOLE 64x256 A-strip (32KB, fragment-ordered) up front with
// ONE barrier, then a barrier-free k-loop: per step 4 B-loads (L2-hot 128KB
// matrix) + 4 LDS reads + 16 MFMAs, compiler free to pipeline across steps.
// (R18's per-step dbuf+barrier chain was latency-serialized: 56us with all
// pipes <25% busy, dur invariant to halving MFMAs.)
// LDS layout: fragment-ordered slot = (((s*4+mt)*4+q)*16+l16)*8, s=k-step.
// mfma_f32_16x16x32_bf16 (m89-verified): A: m=lane&15,k=quad*8+j;
// B: n=lane&15,k=quad*8+j (from WT); C/D: row=quad*4+reg, col=lane&15.
__global__ __launch_bounds__(256) void k_gemm_sA(
    const __bf16* __restrict__ Ah, const __bf16* __restrict__ BTh,
    __bf16* __restrict__ Ch, unsigned char* __restrict__ Cf8, int M, int K) {
  constexpr int NcFull = 256;
  __shared__ __bf16 sA[64 * 256];  // 32 KB
  int tid = threadIdx.x;
  int lane = tid & 63, wave = tid >> 6;
  int quad = lane >> 4, l16 = lane & 15;
  int m0 = blockIdx.x * 64;
  int col0 = wave * 64;
  // ---- stage all of A (8 rounds, coalesced, fragment-ordered) ----
  int srow = tid >> 2;                  // 0..63
  int mtw = srow >> 4, l16w = srow & 15;
  int arow = min(m0 + srow, M - 1);     // clamp: rows >= M never stored
  const __bf16* ag = Ah + (size_t)arow * K;
#pragma unroll
  for (int r = 0; r < 8; r++) {
    int c = (tid & 3) + r * 4;          // 8-elem chunk 0..31
    int s = c >> 2, q = c & 3;
    int slot = (((s * 4 + mtw) * 4 + q) * 16 + l16w) * 8;
    *(bf16x8*)(sA + slot) = *(const bf16x8*)(ag + c * 8);
  }
  __syncthreads();  // the only barrier
  const __bf16* brh = BTh + (size_t)(col0 + l16) * K + quad * 8;
  f32x4 acc[4][4];  // [mt][nt]
#pragma unroll
  for (int mt = 0; mt < 4; mt++)
#pragma unroll
    for (int t = 0; t < 4; t++) acc[mt][t] = (f32x4){0.f, 0.f, 0.f, 0.f};
  for (int s = 0; s < 8; s++) {  // k0 = s*32; no barriers inside
    bf16x8 b_h[4];
#pragma unroll
    for (int t = 0; t < 4; t++)
      b_h[t] = *(const bf16x8*)(brh + (size_t)t * 16 * K + s * 32);
    bf16x8 a_h[4];
#pragma unroll
    for (int mt = 0; mt < 4; mt++)
      a_h[mt] = *(const bf16x8*)(sA + (((s * 4 + mt) * 4 + quad) * 16 + l16) * 8);
#pragma unroll
    for (int t = 0; t < 4; t++) {
#pragma unroll
      for (int mt = 0; mt < 4; mt++) {
        acc[mt][t] = __builtin_amdgcn_mfma_f32_16x16x32_bf16(a_h[mt], b_h[t], acc[mt][t], 0, 0, 0);
      }
    }
  }
#pragma unroll
  for (int mt = 0; mt < 4; mt++) {
#pragma unroll
    for (int t = 0; t < 4; t++) {
#pragma unroll
      for (int r = 0; r < 4; r++) {
        int m = m0 + mt * 16 + quad * 4 + r;
        if (m < M) {
          size_t o = (size_t)m * NcFull + col0 + t * 16 + l16;
          Ch[o] = (__bf16)acc[mt][t][r];
          Cf8[o] = f32_to_fp8(acc[mt][t][r]);
        }
      }
    }
  }
}

// ---------------- MFMA GEMM, no-LDS (layer 3): Ah @ Bh ------------------
template <int NT, int MT>
__global__ __launch_bounds__(256) void k_gemm_split(
    const __bf16* __restrict__ Ah, const __bf16* __restrict__ BTh,
    __bf16* __restrict__ Ch, int M, int K, int NcFull) {
  int lane = threadIdx.x & 63;
  int wave = threadIdx.x >> 6;
  int quad = lane >> 4;
  int l16 = lane & 15;
  int m0 = blockIdx.y * (64 * MT) + wave * (16 * MT);
  int col0 = blockIdx.x * (NT * 16);
  const __bf16* arh[MT];
#pragma unroll
  for (int mt = 0; mt < MT; mt++) {
    int am = min(m0 + mt * 16 + l16, M - 1);
    arh[mt] = Ah + (size_t)am * K + quad * 8;
  }
  const __bf16* brh = BTh + (size_t)(col0 + l16) * K + quad * 8;
  f32x4 acc[MT][NT];
#pragma unroll
  for (int mt = 0; mt < MT; mt++)
#pragma unroll
    for (int t = 0; t < NT; t++) acc[mt][t] = (f32x4){0.f, 0.f, 0.f, 0.f};
  for (int k0 = 0; k0 < K; k0 += 32) {
    bf16x8 a_h[MT], b_h[NT];
#pragma unroll
    for (int mt = 0; mt < MT; mt++) {
      a_h[mt] = *(const bf16x8*)(arh[mt] + k0);
    }
#pragma unroll
    for (int t = 0; t < NT; t++)
      b_h[t] = *(const bf16x8*)(brh + (size_t)t * 16 * K + k0);
#pragma unroll
    for (int t = 0; t < NT; t++) {
#pragma unroll
      for (int mt = 0; mt < MT; mt++) {
        acc[mt][t] = __builtin_amdgcn_mfma_f32_16x16x32_bf16(a_h[mt], b_h[t], acc[mt][t], 0, 0, 0);
      }
    }
  }
#pragma unroll
  for (int mt = 0; mt < MT; mt++) {
#pragma unroll
    for (int t = 0; t < NT; t++) {
#pragma unroll
      for (int r = 0; r < 4; r++) {
        int m = m0 + mt * 16 + quad * 4 + r;
        if (m < M)
          Ch[(size_t)m * NcFull + col0 + t * 16 + l16] = (__bf16)acc[mt][t][r];
      }
    }
  }
}

// ---------------- attention dots (bf16) ----------------
__global__ __launch_bounds__(256) void k_att(const __bf16* __restrict__ Hh,
                                             const float* __restrict__ attS,
                                             const float* __restrict__ attD,
                                             float* __restrict__ aS,
                                             float* __restrict__ aD, int NH, int H) {
  int idx = blockIdx.x * 256 + threadIdx.x;
  if (idx >= NH) return;
  int h = idx % H;
  const bf16x8* hv = (const bf16x8*)(Hh + (size_t)idx * 32);
  const float* sv = attS + h * 32;
  const float* dv = attD + h * 32;
  float ss = 0.f, dd = 0.f;
#pragma unroll
  for (int k = 0; k < 4; k++) {
    bf16x8 a = hv[k];
#pragma unroll
    for (int j = 0; j < 8; j++) {
      float v = (float)a[j];
      ss += v * sv[k * 8 + j];
      dd += v * dv[k * 8 + j];
    }
  }
  aS[idx] = ss;
  aD[idx] = dd;
}

// ---------------- dense edge-parallel alpha (R12) ----------------
__global__ __launch_bounds__(256) void k_edge_alpha8(
    const float* __restrict__ aS, const float* __restrict__ aD,
    const int2* __restrict__ col2,
    __bf16* __restrict__ ealpha, int M) {
  int e = blockIdx.x * 256 + threadIdx.x;
  if (e >= M) return;
  int2 sd = col2[e];
  const float* ap = aS + (size_t)sd.x * 8;
  const float* dp = aD + (size_t)sd.y * 8;
  bf16x8 ev;
#pragma unroll
  for (int h = 0; h < 8; h++) {
    float x = ap[h] + dp[h];
    x = (x > 0.f) ? x : 0.2f * x;
    ev[h] = (__bf16)__expf(x);
  }
  *(bf16x8*)(ealpha + (size_t)e * 8) = ev;
}

__global__ __launch_bounds__(256) void k_edge_alpha1(
    const float* __restrict__ aS, const float* __restrict__ aD,
    const int2* __restrict__ col2,
    __bf16* __restrict__ ealpha, int M) {
  int e = blockIdx.x * 256 + threadIdx.x;
  if (e >= M) return;
  int2 sd = col2[e];
  float x = aS[sd.x] + aD[sd.y];
  x = (x > 0.f) ? x : 0.2f * x;
  ealpha[e] = (__bf16)__expf(x);
}

// ---------------- GAT aggregation, H=8 (R15 shape, bf16-only out) --------
// wave per node, 64 lanes x 4B = contiguous 256B/edge gather, 4-deep
// unroll, per-lane den (no shuffles).
__global__ __launch_bounds__(256) void k_gat_agg8(
    const unsigned char* __restrict__ Hf8, const int* __restrict__ rowptr,
    const int* __restrict__ col_s, const __bf16* __restrict__ ealpha,
    const float* __restrict__ bias, __bf16* __restrict__ outh, int N) {
  int wid = (blockIdx.x * blockDim.x + threadIdx.x) >> 6;
  int lane = threadIdx.x & 63;
  if (wid >= N) return;
  int n = wid;
  int row0 = rowptr[n];
  int deg = rowptr[n + 1] - row0;
  int head = lane >> 3;

  f32x4 acc = (f32x4){0.f, 0.f, 0.f, 0.f};
  float den = 0.f;
  const __bf16* ea = ealpha;
  int i = 0;
  for (; i + 3 < deg; i += 4) {
    int sl = row0 + i;
    int s0 = col_s[sl + 0];
    int s1 = col_s[sl + 1];
    int s2 = col_s[sl + 2];
    int s3 = col_s[sl + 3];
    float w0 = (float)ea[(size_t)(sl + 0) * 8 + head];
    float w1 = (float)ea[(size_t)(sl + 1) * 8 + head];
    float w2 = (float)ea[(size_t)(sl + 2) * 8 + head];
    float w3 = (float)ea[(size_t)(sl + 3) * 8 + head];
    unsigned int p0 = *(const unsigned int*)(Hf8 + (size_t)s0 * 256 + lane * 4);
    unsigned int p1 = *(const unsigned int*)(Hf8 + (size_t)s1 * 256 + lane * 4);
    unsigned int p2 = *(const unsigned int*)(Hf8 + (size_t)s2 * 256 + lane * 4);
    unsigned int p3 = *(const unsigned int*)(Hf8 + (size_t)s3 * 256 + lane * 4);
    den += w0 + w1 + w2 + w3;
    fma_fp8x4(acc, w0, p0);
    fma_fp8x4(acc, w1, p1);
    fma_fp8x4(acc, w2, p2);
    fma_fp8x4(acc, w3, p3);
  }
  for (; i < deg; i++) {
    int sl = row0 + i;
    int s0 = col_s[sl];
    float w0 = (float)ea[(size_t)sl * 8 + head];
    unsigned int p0 = *(const unsigned int*)(Hf8 + (size_t)s0 * 256 + lane * 4);
    den += w0;
    fma_fp8x4(acc, w0, p0);
  }
  float rsv = 1.f / den;  // deg >= 1 (self-loop), den > 0
  float4 bv = *(const float4*)(bias + lane * 4);
  bf16x4 hb;
#pragma unroll
  for (int j = 0; j < 4; j++) {
    float v = acc[j] * rsv + ((const float*)&bv)[j];
    v = (v > 0.f) ? v : (__expf(v) - 1.f);  // ELU
    hb[j] = (__bf16)v;
  }
  *(bf16x4*)(outh + (size_t)n * 256 + lane * 4) = hb;
}

// ---------------- GAT aggregation, H=1 (layer 3, fp32 out, no ELU) ------
__global__ __launch_bounds__(256) void k_gat_agg1(
    const __bf16* __restrict__ Hh, const int* __restrict__ rowptr,
    const int* __restrict__ col_s, const __bf16* __restrict__ ealpha,
    const float* __restrict__ bias, float* __restrict__ out, int N) {
  int wid = (blockIdx.x * blockDim.x + threadIdx.x) >> 6;
  int lane = threadIdx.x & 63;
  if (wid >= N) return;
  int n = wid;
  int row0 = rowptr[n];
  int deg = rowptr[n + 1] - row0;
  int eo = lane >> 3;
  int cl = lane & 7;
  f32x4 acc = (f32x4){0.f, 0.f, 0.f, 0.f};
  float den = 0.f;
  for (int i = eo; i < deg; i += 8) {
    int slot = row0 + i;
    int src = col_s[slot];
    float w = (float)ealpha[slot];
    den += w;
    bf16x4 hv = *(const bf16x4*)(Hh + (size_t)src * 32 + cl * 4);
#pragma unroll
    for (int j = 0; j < 4; j++) acc[j] += w * (float)hv[j];
  }
#pragma unroll
  for (int off = 8; off < 64; off <<= 1) {
#pragma unroll
    for (int j = 0; j < 4; j++) acc[j] += __shfl_xor(acc[j], off, 64);
    den += __shfl_xor(den, off, 64);
  }
  if (eo == 0) {
    float rsv = 1.f / den;
#pragma unroll
    for (int j = 0; j < 4; j++)
      out[(size_t)n * 32 + cl * 4 + j] = acc[j] * rsv + bias[cl * 4 + j];
  }
}

// ---------------- fused mean-pool + linear ----------------
__global__ __launch_bounds__(256) void k_pool_final(
    const float* __restrict__ h, const int* __restrict__ batch,
    const float* __restrict__ linW, const float* __restrict__ linb,
    float* __restrict__ out, int N) {
  __shared__ float sh[256];
  int g = blockIdx.x;
  int tid = threadIdx.x;
  int grp = tid >> 5, c = tid & 31;
  int lo = 0, hi = N;
  while (lo < hi) { int mid = (lo + hi) >> 1; if (batch[mid] < g) lo = mid + 1; else hi = mid; }
  int start = lo;
  hi = N;
  while (lo < hi) { int mid = (lo + hi) >> 1; if (batch[mid] < g + 1) lo = mid + 1; else hi = mid; }
  int end = lo;
  float acc = 0.f;
  for (int n = start + grp; n < end; n += 8) acc += h[(size_t)n * 32 + c];
  sh[tid] = acc;
  __syncthreads();
  if (tid < 32) {
    float s = 0.f;
#pragma unroll
    for (int j = 0; j < 8; j++) s += sh[j * 32 + tid];
    float v = s * linW[tid];
#pragma unroll
    for (int off = 16; off > 0; off >>= 1) v += __shfl_xor(v, off, 64);
    if (tid == 0) {
      float cnt = (float)(end - start);
      out[g] = v / fmaxf(cnt, 1.f) + linb[0];
    }
  }
}

extern "C" void kernel_launch(void* const* d_in, const int* in_sizes, int n_in,
                              void* d_out, int out_size, void* d_ws, size_t ws_size,
                              hipStream_t stream) {
  const float* x = (const float*)d_in[0];
  const int* ei = (const int*)d_in[1];
  const int* batch = (const int*)d_in[2];
  const float* W1 = (const float*)d_in[3];
  const float* as1 = (const float*)d_in[4];
  const float* ad1 = (const float*)d_in[5];
  const float* b1 = (const float*)d_in[6];
  const float* W2 = (const float*)d_in[7];
  const float* as2 = (const float*)d_in[8];
  const float* ad2 = (const float*)d_in[9];
  const float* b2 = (const float*)d_in[10];
  const float* W3 = (const float*)d_in[11];
  const float* as3 = (const float*)d_in[12];
  const float* ad3 = (const float*)d_in[13];
  const float* b3 = (const float*)d_in[14];
  const float* linW = (const float*)d_in[15];
  const float* linb = (const float*)d_in[16];

  const int N = in_sizes[0] / 256;
  const int E = in_sizes[1] / 2;
  const int NUM_GRAPHS = 64;
  float* out = (float*)d_out;

  char* ws = (char*)d_ws;
  size_t off = 0;
  auto alloc = [&](size_t bytes) -> void* {
    void* p = ws + off;
    off += (bytes + 255) & ~(size_t)255;
    return p;
  };
  __bf16* Hh = (__bf16*)alloc((size_t)N * 256 * 2);  // GEMM h out (bf16)
  unsigned char* Hf8 = (unsigned char*)alloc((size_t)N * 256);  // fp8 copy
  __bf16* Ah = (__bf16*)alloc((size_t)N * 256 * 2);  // GEMM A in (bf16)
  __bf16* ealpha = (__bf16*)alloc((size_t)(E + N) * 8 * 2);  // per-edge exps
  float* aS = (float*)alloc((size_t)N * 8 * 4);
  float* aD = (float*)alloc((size_t)N * 8 * 4);
  int* deg = (int*)alloc((size_t)N * 4);
  int* rowptr = (int*)alloc((size_t)(N + 1) * 4);
  int* cursor = (int*)alloc((size_t)(N + 1) * 4);
  int2* col2 = (int2*)alloc((size_t)(E + N) * 8);  // packed (src,dst) per slot
  int* col_s = (int*)alloc((size_t)(E + N) * 4);   // src-only copy
  int* blockSums = (int*)alloc(256 * 4);
  int* blockOffs = (int*)alloc(256 * 4);
  __bf16* WT1h = (__bf16*)alloc(256 * 256 * 2);
  __bf16* WT2h = (__bf16*)alloc(256 * 256 * 2);
  __bf16* WT3h = (__bf16*)alloc(32 * 256 * 2);
  // h3agg reuses Ah (GEMM3 already consumed Ah when agg3 writes)
  float* h3agg = (float*)Ah;

  // --- preps: x cast + W transposes + CSR build ---
  k_cast<<<(N * 64 + 255) / 256, 256, 0, stream>>>(x, Ah, N * 64);
  k_wprep<<<(256 * 256 + 255) / 256, 256, 0, stream>>>(W1, WT1h, 256, 256);
  k_wprep<<<(256 * 256 + 255) / 256, 256, 0, stream>>>(W2, WT2h, 256, 256);
  k_wprep<<<(256 * 32 + 255) / 256, 256, 0, stream>>>(W3, WT3h, 256, 32);
  k_init_deg<<<(N + 255) / 256, 256, 0, stream>>>(deg, N);
  k_count_deg<<<(E + 255) / 256, 256, 0, stream>>>(ei, E, deg);
  const int nb = (N + 256 * SCAN_CH - 1) / (256 * SCAN_CH);  // 49 <= 256
  k_scan_partial<<<nb, 256, 0, stream>>>(deg, blockSums, N);
  k_scan_blocksums<<<1, 256, 0, stream>>>(blockSums, blockOffs, rowptr, nb, N);
  k_scan_final<<<nb, 256, 0, stream>>>(deg, blockOffs, rowptr, cursor, N);
  {
    const int totalItems = E + N;
    const int nch = 256;  // chunks per stripe; grid = 8*256 = 2048 blocks
    const int chunkSz = (totalItems + nch - 1) / nch;
    k_scatter2<<<8 * nch, 256, 0, stream>>>(ei, E, N, cursor, col2, col_s, chunkSz);
  }

  const int aggBlocks = (N + 3) / 4;
  const int gemmBlocks = (N + 63) / 64;  // 64 rows/block, full 256-col width
  const int M = E + N;
  const int edgeBlocks = (M + 255) / 256;
  dim3 g3(1, (N + 63) / 64);

  // --- layer 1 ---
  k_gemm_sA<<<gemmBlocks, 256, 0, stream>>>(Ah, WT1h, Hh, Hf8, N, 256);
  k_att<<<(N * 8 + 255) / 256, 256, 0, stream>>>(Hh, as1, ad1, aS, aD, N * 8, 8);
  k_edge_alpha8<<<edgeBlocks, 256, 0, stream>>>(aS, aD, col2, ealpha, M);
  k_gat_agg8<<<aggBlocks, 256, 0, stream>>>(Hf8, rowptr, col_s, ealpha, b1,
                                            Ah, N);
  // --- layer 2 ---
  k_gemm_sA<<<gemmBlocks, 256, 0, stream>>>(Ah, WT2h, Hh, Hf8, N, 256);
  k_att<<<(N * 8 + 255) / 256, 256, 0, stream>>>(Hh, as2, ad2, aS, aD, N * 8, 8);
  k_edge_alpha8<<<edgeBlocks, 256, 0, stream>>>(aS, aD, col2, ealpha, M);
  k_gat_agg8<<<aggBlocks, 256, 0, stream>>>(Hf8, rowptr, col_s, ealpha, b2,
                                            Ah, N);
  // --- layer 3 (H=1, bf16 gather) ---
  k_gemm_split<2, 1><<<g3, 256, 0, stream>>>(Ah, WT3h, Hh, N, 256, 32);
  k_att<<<(N + 255) / 256, 256, 0, stream>>>(Hh, as3, ad3, aS, aD, N, 1);
  k_edge_alpha1<<<edgeBlocks, 256, 0, stream>>>(aS, aD, col2, ealpha, M);
  k_gat_agg1<<<aggBlocks, 256, 0, stream>>>(Hh, rowptr, col_s, ealpha, b3,
                                            h3agg, N);
  // --- pool + final ---
  k_pool_final<<<NUM_GRAPHS, 256, 0, stream>>>(h3agg, batch, linW, linb, out, N);
}

// Round 6
// 463.035 us; speedup vs baseline: 1.3319x; 1.0431x over previous
//
#include <hip/hip_runtime.h>
#include <hip/hip_fp8.h>
#include <math.h>

// ---------------------------------------------------------------------------
// GATClassifier on MI355X.
//   1. CSR build over dst (histogram -> 3-phase scan -> dst-STRIPED scatter:
//      stripe = bid&7 so all writers of a col2 line / cursor[d] land on one
//      XCD; (src,dst) packed int2 only — R20 dropped the col_s copy: the
//      second random-store stream re-amplified writes (48MB for 10MB
//      payload); agg reads col2[].x instead.
//   2. Per layer: MFMA GEMM h = bf16(A) @ bf16(B) (R18: split-lo dropped;
//      fp8-gather error dominates, absmax 2.4e-4 passes). R19: single-barrier
//      full-A-stage GEMM (stage 64x256 A-strip, 32KB fragment-ordered, ONE
//      barrier, barrier-free k-loop) — took gemm off the top-5 (was 56us
//      latency-serialized). h stored bf16 + flat fp8 copy.
//      R20 agg8f: wave per node, lane=(edge-group g, 16-channel block c):
//      one dwordx4 gather serves 4 edges/wave-inst (~8 VALU-inst/edge vs 17
//      in the 4B/lane shape — agg was instruction-issue-bound, VALUBusy 51%),
//      2-quad unroll, alpha FUSED (w = exp(leaky(aS[s]+aD[n])) inline; aS is
//      1.6MB L2-resident) -> k_edge_alpha* kernels and ealpha buffer deleted.
//      Cross-group shfl reduce (16,32) + bias/ELU epilogue on g==0 lanes.
//      (R17's failed 16-lane shape split QUARTERS across waves w/ degmax
//      imbalance; here all groups walk the same node's list.)
//   3. Fused mean-pool + 32->1 linear (batch sorted -> binary search)
// History: R2 pool 383. R3 SGEMM 158x2. R4 agg 155x2. R5 gemm 140x2. R6 agg
// 131x2. R7 scan 111. R8 agg 87x2. R9 gemm 89x2. R10 agg 80x2. R11 agg 71x2.
// R12 gemm 57x2. R13 32-row dbuf REGRESSED. R14 64-row dbuf + drop Bl (512).
// R15 striped int2 scatter (506). R16 quartered agg REGRESSED (102x2).
// R17 requartered REGRESSED (83x2). R18 drop lo-terms (488). R19 single-
// barrier GEMM (483; agg 44x2, scatter 45). R20 agg8f fused + packed gather.
// NOTE: edge_index / batch are int32.
// ---------------------------------------------------------------------------

typedef __attribute__((ext_vector_type(8))) __bf16 bf16x8;
typedef __attribute__((ext_vector_type(4))) __bf16 bf16x4;
typedef __attribute__((ext_vector_type(4))) float f32x4;
typedef __attribute__((ext_vector_type(2))) float f32x2;

#define SCAN_CH 4  // elements per thread in the device-wide scan

__device__ inline unsigned char f32_to_fp8(float f) {
  __hip_fp8_e4m3 v(f);
  return (unsigned char)v.__x;
}
__device__ inline float fp8_to_f32(unsigned char u) {
  __hip_fp8_e4m3 v;
  v.__x = (__hip_fp8_storage_t)u;
  return (float)v;
}

// Decode 4 packed fp8-e4m3 bytes -> 4 floats, accumulate w * val into acc.
__device__ inline void fma_fp8x4(f32x4& acc, float w, unsigned int packed) {
#if defined(__has_builtin) && __has_builtin(__builtin_amdgcn_cvt_pk_f32_fp8)
  f32x2 lo = __builtin_amdgcn_cvt_pk_f32_fp8((int)packed, false);  // bytes 0,1
  f32x2 hi = __builtin_amdgcn_cvt_pk_f32_fp8((int)packed, true);   // bytes 2,3
  acc[0] += w * lo[0];
  acc[1] += w * lo[1];
  acc[2] += w * hi[0];
  acc[3] += w * hi[1];
#else
  acc[0] += w * fp8_to_f32((unsigned char)(packed & 0xff));
  acc[1] += w * fp8_to_f32((unsigned char)((packed >> 8) & 0xff));
  acc[2] += w * fp8_to_f32((unsigned char)((packed >> 16) & 0xff));
  acc[3] += w * fp8_to_f32((unsigned char)(packed >> 24));
#endif
}

// ---------------- CSR build ----------------
__global__ __launch_bounds__(256) void k_init_deg(int* deg, int N) {
  int n = blockIdx.x * 256 + threadIdx.x;
  if (n < N) deg[n] = 1;  // self-loop
}

__global__ __launch_bounds__(256) void k_count_deg(const int* __restrict__ ei,
                                                   int E, int* deg) {
  int e = blockIdx.x * 256 + threadIdx.x;
  if (e < E) atomicAdd(&deg[ei[E + e]], 1);
}

// --- 3-phase exclusive scan (R8: old single-block scan was 111us on 1 CU) ---
__global__ __launch_bounds__(256) void k_scan_partial(const int* __restrict__ deg,
                                                      int* __restrict__ blockSums,
                                                      int N) {
  __shared__ int sh[256];
  int t = threadIdx.x, b = blockIdx.x;
  int base = (b * 256 + t) * SCAN_CH;
  int s = 0;
#pragma unroll
  for (int j = 0; j < SCAN_CH; j++) {
    int idx = base + j;
    if (idx < N) s += deg[idx];
  }
  sh[t] = s;
  __syncthreads();
  for (int off = 128; off > 0; off >>= 1) {
    if (t < off) sh[t] += sh[t + off];
    __syncthreads();
  }
  if (t == 0) blockSums[b] = sh[0];
}

__global__ __launch_bounds__(256) void k_scan_blocksums(
    const int* __restrict__ blockSums, int* __restrict__ blockOffs,
    int* __restrict__ rowptr, int nb, int N) {
  __shared__ int sh[256];
  int t = threadIdx.x;
  int v = (t < nb) ? blockSums[t] : 0;
  sh[t] = v;
  __syncthreads();
  for (int off = 1; off < 256; off <<= 1) {
    int u = (t >= off) ? sh[t - off] : 0;
    __syncthreads();
    sh[t] += u;
    __syncthreads();
  }
  if (t < nb) blockOffs[t] = sh[t] - v;  // exclusive
  if (t == nb - 1) rowptr[N] = sh[t];    // total
}

__global__ __launch_bounds__(256) void k_scan_final(const int* __restrict__ deg,
                                                    const int* __restrict__ blockOffs,
                                                    int* __restrict__ rowptr,
                                                    int* __restrict__ cursor, int N) {
  __shared__ int sh[256];
  int t = threadIdx.x, b = blockIdx.x;
  int base = (b * 256 + t) * SCAN_CH;
  int vals[SCAN_CH];
  int s = 0;
#pragma unroll
  for (int j = 0; j < SCAN_CH; j++) {
    int idx = base + j;
    vals[j] = (idx < N) ? deg[idx] : 0;
    s += vals[j];
  }
  sh[t] = s;
  __syncthreads();
  for (int off = 1; off < 256; off <<= 1) {
    int u = (t >= off) ? sh[t - off] : 0;
    __syncthreads();
    sh[t] += u;
    __syncthreads();
  }
  int run = blockOffs[b] + sh[t] - s;  // exclusive prefix for this thread
#pragma unroll
  for (int j = 0; j < SCAN_CH; j++) {
    int idx = base + j;
    if (idx < N) {
      rowptr[idx] = run;
      cursor[idx] = run;
      run += vals[j];
    }
  }
}

// dst-striped scatter (R15/R20). Grid = 8 stripes x nch chunks; stripe =
// bid&7 (matches HW round-robin block->XCD, heuristic only). Single packed
// int2 store per edge (R20: col_s dropped — its second random-store stream
// re-amplified HBM writes).
__global__ __launch_bounds__(256) void k_scatter2(const int* __restrict__ ei,
                                                  int E, int N, int* cursor,
                                                  int2* __restrict__ col2,
                                                  int chunkSz) {
  int stripe = blockIdx.x & 7;
  int chunk = blockIdx.x >> 3;
  int lo = (int)(((long long)N * stripe) >> 3);
  int hi = (int)(((long long)N * (stripe + 1)) >> 3);
  int base = chunk * chunkSz;
  int end = base + chunkSz;
  int total = E + N;
  if (end > total) end = total;
  for (int i = base + threadIdx.x; i < end; i += 256) {
    int d = (i < E) ? ei[E + i] : (i - E);
    if (d < lo || d >= hi) continue;
    int s = (i < E) ? ei[i] : d;
    int pos = atomicAdd(&cursor[d], 1);
    col2[pos] = make_int2(s, d);
  }
}

// ---------------- cast prep (plain bf16) ----------------
__global__ __launch_bounds__(256) void k_cast(const float* __restrict__ in,
                                              __bf16* __restrict__ oh, int n4) {
  int i = blockIdx.x * 256 + threadIdx.x;
  if (i >= n4) return;
  float4 v = ((const float4*)in)[i];
  bf16x4 h;
  h[0] = (__bf16)v.x;
  h[1] = (__bf16)v.y;
  h[2] = (__bf16)v.z;
  h[3] = (__bf16)v.w;
  ((bf16x4*)oh)[i] = h;
}

// W [K][Nc] fp32 -> WT [Nc][K] plain bf16.
__global__ __launch_bounds__(256) void k_wprep(const float* __restrict__ W,
                                               __bf16* __restrict__ WTh,
                                               int K, int Nc) {
  int i = blockIdx.x * 256 + threadIdx.x;  // i = n*K + k
  if (i >= K * Nc) return;
  int n = i / K, k = i - n * K;
  WTh[i] = (__bf16)W[k * Nc + n];
}

// ---------------- LDS-shared MFMA GEMM (layers 1/2, R19) -----------------
// C = Ah @ Bh, plain bf16. Block = 64 rows x 256 cols (782 blocks, 4 waves).
// Stage the WHOLE 64x256 A-strip (32KB, fragment-ordered) up front, ONE
// barrier, then barrier-free k-loop: 4 B-loads + 4 LDS reads + 16 MFMAs per
// step; compiler pipelines across steps.
// mfma_f32_16x16x32_bf16 (m89-verified): A: m=lane&15,k=quad*8+j;
// B: n=lane&15,k=quad*8+j (from WT); C/D: row=quad*4+reg, col=lane&15.
__global__ __launch_bounds__(256) void k_gemm_sA(
    const __bf16* __restrict__ Ah, const __bf16* __restrict__ BTh,
    __bf16* __restrict__ Ch, unsigned char* __restrict__ Cf8, int M, int K) {
  constexpr int NcFull = 256;
  __shared__ __bf16 sA[64 * 256];  // 32 KB
  int tid = threadIdx.x;
  int lane = tid & 63, wave = tid >> 6;
  int quad = lane >> 4, l16 = lane & 15;
  int m0 = blockIdx.x * 64;
  int col0 = wave * 64;
  // ---- stage all of A (8 rounds, coalesced, fragment-ordered) ----
  int srow = tid >> 2;                  // 0..63
  int mtw = srow >> 4, l16w = srow & 15;
  int arow = min(m0 + srow, M - 1);     // clamp: rows >= M never stored
  const __bf16* ag = Ah + (size_t)arow * K;
#pragma unroll
  for (int r = 0; r < 8; r++) {
    int c = (tid & 3) + r * 4;          // 8-elem chunk 0..31
    int s = c >> 2, q = c & 3;
    int slot = (((s * 4 + mtw) * 4 + q) * 16 + l16w) * 8;
    *(bf16x8*)(sA + slot) = *(const bf16x8*)(ag + c * 8);
  }
  __syncthreads();  // the only barrier
  const __bf16* brh = BTh + (size_t)(col0 + l16) * K + quad * 8;
  f32x4 acc[4][4];  // [mt][nt]
#pragma unroll
  for (int mt = 0; mt < 4; mt++)
#pragma unroll
    for (int t = 0; t < 4; t++) acc[mt][t] = (f32x4){0.f, 0.f, 0.f, 0.f};
  for (int s = 0; s < 8; s++) {  // k0 = s*32; no barriers inside
    bf16x8 b_h[4];
#pragma unroll
    for (int t = 0; t < 4; t++)
      b_h[t] = *(const bf16x8*)(brh + (size_t)t * 16 * K + s * 32);
    bf16x8 a_h[4];
#pragma unroll
    for (int mt = 0; mt < 4; mt++)
      a_h[mt] = *(const bf16x8*)(sA + (((s * 4 + mt) * 4 + quad) * 16 + l16) * 8);
#pragma unroll
    for (int t = 0; t < 4; t++) {
#pragma unroll
      for (int mt = 0; mt < 4; mt++) {
        acc[mt][t] = __builtin_amdgcn_mfma_f32_16x16x32_bf16(a_h[mt], b_h[t], acc[mt][t], 0, 0, 0);
      }
    }
  }
#pragma unroll
  for (int mt = 0; mt < 4; mt++) {
#pragma unroll
    for (int t = 0; t < 4; t++) {
#pragma unroll
      for (int r = 0; r < 4; r++) {
        int m = m0 + mt * 16 + quad * 4 + r;
        if (m < M) {
          size_t o = (size_t)m * NcFull + col0 + t * 16 + l16;
          Ch[o] = (__bf16)acc[mt][t][r];
          Cf8[o] = f32_to_fp8(acc[mt][t][r]);
        }
      }
    }
  }
}

// ---------------- MFMA GEMM, no-LDS (layer 3): Ah @ Bh ------------------
template <int NT, int MT>
__global__ __launch_bounds__(256) void k_gemm_split(
    const __bf16* __restrict__ Ah, const __bf16* __restrict__ BTh,
    __bf16* __restrict__ Ch, int M, int K, int NcFull) {
  int lane = threadIdx.x & 63;
  int wave = threadIdx.x >> 6;
  int quad = lane >> 4;
  int l16 = lane & 15;
  int m0 = blockIdx.y * (64 * MT) + wave * (16 * MT);
  int col0 = blockIdx.x * (NT * 16);
  const __bf16* arh[MT];
#pragma unroll
  for (int mt = 0; mt < MT; mt++) {
    int am = min(m0 + mt * 16 + l16, M - 1);
    arh[mt] = Ah + (size_t)am * K + quad * 8;
  }
  const __bf16* brh = BTh + (size_t)(col0 + l16) * K + quad * 8;
  f32x4 acc[MT][NT];
#pragma unroll
  for (int mt = 0; mt < MT; mt++)
#pragma unroll
    for (int t = 0; t < NT; t++) acc[mt][t] = (f32x4){0.f, 0.f, 0.f, 0.f};
  for (int k0 = 0; k0 < K; k0 += 32) {
    bf16x8 a_h[MT], b_h[NT];
#pragma unroll
    for (int mt = 0; mt < MT; mt++) {
      a_h[mt] = *(const bf16x8*)(arh[mt] + k0);
    }
#pragma unroll
    for (int t = 0; t < NT; t++)
      b_h[t] = *(const bf16x8*)(brh + (size_t)t * 16 * K + k0);
#pragma unroll
    for (int t = 0; t < NT; t++) {
#pragma unroll
      for (int mt = 0; mt < MT; mt++) {
        acc[mt][t] = __builtin_amdgcn_mfma_f32_16x16x32_bf16(a_h[mt], b_h[t], acc[mt][t], 0, 0, 0);
      }
    }
  }
#pragma unroll
  for (int mt = 0; mt < MT; mt++) {
#pragma unroll
    for (int t = 0; t < NT; t++) {
#pragma unroll
      for (int r = 0; r < 4; r++) {
        int m = m0 + mt * 16 + quad * 4 + r;
        if (m < M)
          Ch[(size_t)m * NcFull + col0 + t * 16 + l16] = (__bf16)acc[mt][t][r];
      }
    }
  }
}

// ---------------- attention dots (bf16) ----------------
__global__ __launch_bounds__(256) void k_att(const __bf16* __restrict__ Hh,
                                             const float* __restrict__ attS,
                                             const float* __restrict__ attD,
                                             float* __restrict__ aS,
                                             float* __restrict__ aD, int NH, int H) {
  int idx = blockIdx.x * 256 + threadIdx.x;
  if (idx >= NH) return;
  int h = idx % H;
  const bf16x8* hv = (const bf16x8*)(Hh + (size_t)idx * 32);
  const float* sv = attS + h * 32;
  const float* dv = attD + h * 32;
  float ss = 0.f, dd = 0.f;
#pragma unroll
  for (int k = 0; k < 4; k++) {
    bf16x8 a = hv[k];
#pragma unroll
    for (int j = 0; j < 8; j++) {
      float v = (float)a[j];
      ss += v * sv[k * 8 + j];
      dd += v * dv[k * 8 + j];
    }
  }
  aS[idx] = ss;
  aD[idx] = dd;
}

// ---------------- GAT aggregation, H=8, fused alpha (R20) ----------------
// wave per node. lane = (edge-group g = lane>>4, channel-block c = lane&15:
// 16 fp8 channels = one dwordx4). One gather instruction serves 4 edges.
// w = exp(leaky(aS[s*8+head] + aD[n*8+head])) computed inline (head = c>>1;
// aS 1.6MB L2-resident). 2-quad unroll = 2 gathers in flight. Cross-group
// shfl reduce (xor 16,32), then g==0 lanes do bias+ELU and write 32B each.
__global__ __launch_bounds__(256) void k_gat_agg8f(
    const unsigned char* __restrict__ Hf8, const int* __restrict__ rowptr,
    const int2* __restrict__ col2, const float* __restrict__ aS,
    const float* __restrict__ aD, const float* __restrict__ bias,
    __bf16* __restrict__ outh, int N) {
  int wid = (blockIdx.x * blockDim.x + threadIdx.x) >> 6;
  int lane = threadIdx.x & 63;
  if (wid >= N) return;
  int n = wid;
  int row0 = rowptr[n];
  int deg = rowptr[n + 1] - row0;
  int g = lane >> 4;   // edge group 0..3
  int c = lane & 15;   // channel block (16 fp8 = 16B)
  int head = c >> 1;
  float ad = aD[(size_t)n * 8 + head];
  f32x4 acc0 = (f32x4){0.f, 0.f, 0.f, 0.f};
  f32x4 acc1 = (f32x4){0.f, 0.f, 0.f, 0.f};
  f32x4 acc2 = (f32x4){0.f, 0.f, 0.f, 0.f};
  f32x4 acc3 = (f32x4){0.f, 0.f, 0.f, 0.f};
  float den = 0.f;
  int dm1 = deg - 1;
  const int* colx = (const int*)col2;  // .x at stride 2
  for (int i = 0; i < deg; i += 8) {
    int e0 = i + g, e1 = i + 4 + g;
    int sl0 = row0 + min(e0, dm1);
    int sl1 = row0 + min(e1, dm1);
    int s0 = colx[(size_t)sl0 * 2];
    int s1 = colx[(size_t)sl1 * 2];
    uint4 p0 = *(const uint4*)(Hf8 + (size_t)s0 * 256 + c * 16);
    uint4 p1 = *(const uint4*)(Hf8 + (size_t)s1 * 256 + c * 16);
    float w0 = 0.f, w1 = 0.f;
    if (e0 < deg) {
      float x = aS[(size_t)s0 * 8 + head] + ad;
      x = (x > 0.f) ? x : 0.2f * x;
      w0 = __expf(x);
    }
    if (e1 < deg) {
      float x = aS[(size_t)s1 * 8 + head] + ad;
      x = (x > 0.f) ? x : 0.2f * x;
      w1 = __expf(x);
    }
    den += w0 + w1;
    fma_fp8x4(acc0, w0, p0.x);
    fma_fp8x4(acc1, w0, p0.y);
    fma_fp8x4(acc2, w0, p0.z);
    fma_fp8x4(acc3, w0, p0.w);
    fma_fp8x4(acc0, w1, p1.x);
    fma_fp8x4(acc1, w1, p1.y);
    fma_fp8x4(acc2, w1, p1.z);
    fma_fp8x4(acc3, w1, p1.w);
  }
  // reduce across the 4 edge-groups (lane bits 4,5)
#pragma unroll
  for (int off = 16; off < 64; off <<= 1) {
#pragma unroll
    for (int j = 0; j < 4; j++) {
      acc0[j] += __shfl_xor(acc0[j], off, 64);
      acc1[j] += __shfl_xor(acc1[j], off, 64);
      acc2[j] += __shfl_xor(acc2[j], off, 64);
      acc3[j] += __shfl_xor(acc3[j], off, 64);
    }
    den += __shfl_xor(den, off, 64);
  }
  if (g == 0) {
    float rsv = 1.f / den;  // deg >= 1 (self-loop), den > 0
    const float4* bp = (const float4*)(bias + c * 16);
    float4 b0 = bp[0], b1 = bp[1], b2 = bp[2], b3 = bp[3];
    bf16x8 o0, o1;
#pragma unroll
    for (int j = 0; j < 4; j++) {
      float v0 = acc0[j] * rsv + ((const float*)&b0)[j];
      float v1 = acc1[j] * rsv + ((const float*)&b1)[j];
      float v2 = acc2[j] * rsv + ((const float*)&b2)[j];
      float v3 = acc3[j] * rsv + ((const float*)&b3)[j];
      v0 = (v0 > 0.f) ? v0 : (__expf(v0) - 1.f);  // ELU
      v1 = (v1 > 0.f) ? v1 : (__expf(v1) - 1.f);
      v2 = (v2 > 0.f) ? v2 : (__expf(v2) - 1.f);
      v3 = (v3 > 0.f) ? v3 : (__expf(v3) - 1.f);
      o0[j] = (__bf16)v0;
      o0[j + 4] = (__bf16)v1;
      o1[j] = (__bf16)v2;
      o1[j + 4] = (__bf16)v3;
    }
    *(bf16x8*)(outh + (size_t)n * 256 + c * 16) = o0;
    *(bf16x8*)(outh + (size_t)n * 256 + c * 16 + 8) = o1;
  }
}

// ---------------- GAT aggregation, H=1, fused alpha (layer 3) -----------
__global__ __launch_bounds__(256) void k_gat_agg1f(
    const __bf16* __restrict__ Hh, const int* __restrict__ rowptr,
    const int2* __restrict__ col2, const float* __restrict__ aS,
    const float* __restrict__ aD, const float* __restrict__ bias,
    float* __restrict__ out, int N) {
  int wid = (blockIdx.x * blockDim.x + threadIdx.x) >> 6;
  int lane = threadIdx.x & 63;
  if (wid >= N) return;
  int n = wid;
  int row0 = rowptr[n];
  int deg = rowptr[n + 1] - row0;
  int eo = lane >> 3;
  int cl = lane & 7;
  float ad = aD[n];
  const int* colx = (const int*)col2;
  f32x4 acc = (f32x4){0.f, 0.f, 0.f, 0.f};
  float den = 0.f;
  for (int i = eo; i < deg; i += 8) {
    int slot = row0 + i;
    int src = colx[(size_t)slot * 2];
    float x = aS[src] + ad;
    x = (x > 0.f) ? x : 0.2f * x;
    float w = __expf(x);
    den += w;
    bf16x4 hv = *(const bf16x4*)(Hh + (size_t)src * 32 + cl * 4);
#pragma unroll
    for (int j = 0; j < 4; j++) acc[j] += w * (float)hv[j];
  }
#pragma unroll
  for (int off = 8; off < 64; off <<= 1) {
#pragma unroll
    for (int j = 0; j < 4; j++) acc[j] += __shfl_xor(acc[j], off, 64);
    den += __shfl_xor(den, off, 64);
  }
  if (eo == 0) {
    float rsv = 1.f / den;
#pragma unroll
    for (int j = 0; j < 4; j++)
      out[(size_t)n * 32 + cl * 4 + j] = acc[j] * rsv + bias[cl * 4 + j];
  }
}

// ---------------- fused mean-pool + linear ----------------
__global__ __launch_bounds__(256) void k_pool_final(
    const float* __restrict__ h, const int* __restrict__ batch,
    const float* __restrict__ linW, const float* __restrict__ linb,
    float* __restrict__ out, int N) {
  __shared__ float sh[256];
  int g = blockIdx.x;
  int tid = threadIdx.x;
  int grp = tid >> 5, c = tid & 31;
  int lo = 0, hi = N;
  while (lo < hi) { int mid = (lo + hi) >> 1; if (batch[mid] < g) lo = mid + 1; else hi = mid; }
  int start = lo;
  hi = N;
  while (lo < hi) { int mid = (lo + hi) >> 1; if (batch[mid] < g + 1) lo = mid + 1; else hi = mid; }
  int end = lo;
  float acc = 0.f;
  for (int n = start + grp; n < end; n += 8) acc += h[(size_t)n * 32 + c];
  sh[tid] = acc;
  __syncthreads();
  if (tid < 32) {
    float s = 0.f;
#pragma unroll
    for (int j = 0; j < 8; j++) s += sh[j * 32 + tid];
    float v = s * linW[tid];
#pragma unroll
    for (int off = 16; off > 0; off >>= 1) v += __shfl_xor(v, off, 64);
    if (tid == 0) {
      float cnt = (float)(end - start);
      out[g] = v / fmaxf(cnt, 1.f) + linb[0];
    }
  }
}

extern "C" void kernel_launch(void* const* d_in, const int* in_sizes, int n_in,
                              void* d_out, int out_size, void* d_ws, size_t ws_size,
                              hipStream_t stream) {
  const float* x = (const float*)d_in[0];
  const int* ei = (const int*)d_in[1];
  const int* batch = (const int*)d_in[2];
  const float* W1 = (const float*)d_in[3];
  const float* as1 = (const float*)d_in[4];
  const float* ad1 = (const float*)d_in[5];
  const float* b1 = (const float*)d_in[6];
  const float* W2 = (const float*)d_in[7];
  const float* as2 = (const float*)d_in[8];
  const float* ad2 = (const float*)d_in[9];
  const float* b2 = (const float*)d_in[10];
  const float* W3 = (const float*)d_in[11];
  const float* as3 = (const float*)d_in[12];
  const float* ad3 = (const float*)d_in[13];
  const float* b3 = (const float*)d_in[14];
  const float* linW = (const float*)d_in[15];
  const float* linb = (const float*)d_in[16];

  const int N = in_sizes[0] / 256;
  const int E = in_sizes[1] / 2;
  const int NUM_GRAPHS = 64;
  float* out = (float*)d_out;

  char* ws = (char*)d_ws;
  size_t off = 0;
  auto alloc = [&](size_t bytes) -> void* {
    void* p = ws + off;
    off += (bytes + 255) & ~(size_t)255;
    return p;
  };
  __bf16* Hh = (__bf16*)alloc((size_t)N * 256 * 2);  // GEMM h out (bf16)
  unsigned char* Hf8 = (unsigned char*)alloc((size_t)N * 256);  // fp8 copy
  __bf16* Ah = (__bf16*)alloc((size_t)N * 256 * 2);  // GEMM A in (bf16)
  float* aS = (float*)alloc((size_t)N * 8 * 4);
  float* aD = (float*)alloc((size_t)N * 8 * 4);
  int* deg = (int*)alloc((size_t)N * 4);
  int* rowptr = (int*)alloc((size_t)(N + 1) * 4);
  int* cursor = (int*)alloc((size_t)(N + 1) * 4);
  int2* col2 = (int2*)alloc((size_t)(E + N) * 8);  // packed (src,dst) per slot
  int* blockSums = (int*)alloc(256 * 4);
  int* blockOffs = (int*)alloc(256 * 4);
  __bf16* WT1h = (__bf16*)alloc(256 * 256 * 2);
  __bf16* WT2h = (__bf16*)alloc(256 * 256 * 2);
  __bf16* WT3h = (__bf16*)alloc(32 * 256 * 2);
  // h3agg reuses Ah (GEMM3 already consumed Ah when agg3 writes)
  float* h3agg = (float*)Ah;

  // --- preps: x cast + W transposes + CSR build ---
  k_cast<<<(N * 64 + 255) / 256, 256, 0, stream>>>(x, Ah, N * 64);
  k_wprep<<<(256 * 256 + 255) / 256, 256, 0, stream>>>(W1, WT1h, 256, 256);
  k_wprep<<<(256 * 256 + 255) / 256, 256, 0, stream>>>(W2, WT2h, 256, 256);
  k_wprep<<<(256 * 32 + 255) / 256, 256, 0, stream>>>(W3, WT3h, 256, 32);
  k_init_deg<<<(N + 255) / 256, 256, 0, stream>>>(deg, N);
  k_count_deg<<<(E + 255) / 256, 256, 0, stream>>>(ei, E, deg);
  const int nb = (N + 256 * SCAN_CH - 1) / (256 * SCAN_CH);  // 49 <= 256
  k_scan_partial<<<nb, 256, 0, stream>>>(deg, blockSums, N);
  k_scan_blocksums<<<1, 256, 0, stream>>>(blockSums, blockOffs, rowptr, nb, N);
  k_scan_final<<<nb, 256, 0, stream>>>(deg, blockOffs, rowptr, cursor, N);
  {
    const int totalItems = E + N;
    const int nch = 256;  // chunks per stripe; grid = 8*256 = 2048 blocks
    const int chunkSz = (totalItems + nch - 1) / nch;
    k_scatter2<<<8 * nch, 256, 0, stream>>>(ei, E, N, cursor, col2, chunkSz);
  }

  const int aggBlocks = (N + 3) / 4;
  const int gemmBlocks = (N + 63) / 64;  // 64 rows/block, full 256-col width
  dim3 g3(1, (N + 63) / 64);

  // --- layer 1 ---
  k_gemm_sA<<<gemmBlocks, 256, 0, stream>>>(Ah, WT1h, Hh, Hf8, N, 256);
  k_att<<<(N * 8 + 255) / 256, 256, 0, stream>>>(Hh, as1, ad1, aS, aD, N * 8, 8);
  k_gat_agg8f<<<aggBlocks, 256, 0, stream>>>(Hf8, rowptr, col2, aS, aD, b1,
                                             Ah, N);
  // --- layer 2 ---
  k_gemm_sA<<<gemmBlocks, 256, 0, stream>>>(Ah, WT2h, Hh, Hf8, N, 256);
  k_att<<<(N * 8 + 255) / 256, 256, 0, stream>>>(Hh, as2, ad2, aS, aD, N * 8, 8);
  k_gat_agg8f<<<aggBlocks, 256, 0, stream>>>(Hf8, rowptr, col2, aS, aD, b2,
                                             Ah, N);
  // --- layer 3 (H=1, bf16 gather) ---
  k_gemm_split<2, 1><<<g3, 256, 0, stream>>>(Ah, WT3h, Hh, N, 256, 32);
  k_att<<<(N + 255) / 256, 256, 0, stream>>>(Hh, as3, ad3, aS, aD, N, 1);
  k_gat_agg1f<<<aggBlocks, 256, 0, stream>>>(Hh, rowptr, col2, aS, aD, b3,
                                             h3agg, N);
  // --- pool + final ---
  k_pool_final<<<NUM_GRAPHS, 256, 0, stream>>>(h3agg, batch, linW, linb, out, N);
}

// Round 7
// 448.128 us; speedup vs baseline: 1.3762x; 1.0333x over previous
//
#include <hip/hip_runtime.h>
#include <hip/hip_fp8.h>
#include <math.h>

// ---------------------------------------------------------------------------
// GATClassifier on MI355X.
//   1. CSR build over dst (histogram -> 3-phase scan -> dst-STRIPED scatter:
//      stripe = bid&7 so all writers of a col line / cursor[d] land on one
//      XCD. R21: col2 int2 -> col_s int4B ONLY — nothing reads dst anymore
//      (alpha fused in R20; dst implicit in rowptr walk). Halves scatter's
//      random-store bytes and agg's col stream.
//   2. Per layer: MFMA GEMM h = bf16(A) @ bf16(B) (R18: split-lo dropped;
//      fp8-gather error dominates, absmax ~2e-4 passes). R19 single-barrier
//      full-A-stage GEMM (64x256 A-strip in 32KB LDS, fragment-ordered,
//      barrier-free k-loop). R21: ATT DOTS FUSED into the GEMM epilogue —
//      wave w owns cols 64w..64w+63 = heads 2w,2w+1 exactly, so after the
//      k-loop: barrier, spill h bf16 into sA (reuse), barrier, 512
//      (row,head) dot tasks from LDS -> aS/aD. Deletes k_att for layers 1/2
//      and their 25.6MB Hh re-reads. h stored bf16 + flat fp8 copy.
//      R20 agg8f: wave per node, lane=(edge-group g, 16-ch block c), one
//      dwordx4 gather serves 4 edges/inst, alpha inline
//      (w = exp(leaky(aS[s]+aD[n])), aS 1.6MB L2-resident), cross-group
//      shfl reduce + bias/ELU on g==0.
//   3. Fused mean-pool + 32->1 linear (batch sorted -> binary search)
// History: R2 pool 383. R3 SGEMM 158x2. R4 agg 155x2. R5 gemm 140x2. R6 agg
// 131x2. R7 scan 111. R8 agg 87x2. R9 gemm 89x2. R10 agg 80x2. R11 agg 71x2.
// R12 gemm 57x2. R13 32-row dbuf REGRESSED. R14 64-row dbuf + drop Bl (512).
// R15 striped int2 scatter (506). R16 quartered agg REGRESSED (102x2).
// R17 requartered REGRESSED (83x2). R18 drop lo-terms (488). R19 single-
// barrier GEMM (483). R20 agg8f fused alpha (463; agg 50x2 VALU-bound 71%).
// R21 col_s-only scatter + att fused into GEMM epilogue.
// NOTE: edge_index / batch are int32.
// ---------------------------------------------------------------------------

typedef __attribute__((ext_vector_type(8))) __bf16 bf16x8;
typedef __attribute__((ext_vector_type(4))) __bf16 bf16x4;
typedef __attribute__((ext_vector_type(4))) float f32x4;
typedef __attribute__((ext_vector_type(2))) float f32x2;

#define SCAN_CH 4  // elements per thread in the device-wide scan

__device__ inline unsigned char f32_to_fp8(float f) {
  __hip_fp8_e4m3 v(f);
  return (unsigned char)v.__x;
}
__device__ inline float fp8_to_f32(unsigned char u) {
  __hip_fp8_e4m3 v;
  v.__x = (__hip_fp8_storage_t)u;
  return (float)v;
}

// Decode 4 packed fp8-e4m3 bytes -> 4 floats, accumulate w * val into acc.
__device__ inline void fma_fp8x4(f32x4& acc, float w, unsigned int packed) {
#if defined(__has_builtin) && __has_builtin(__builtin_amdgcn_cvt_pk_f32_fp8)
  f32x2 lo = __builtin_amdgcn_cvt_pk_f32_fp8((int)packed, false);  // bytes 0,1
  f32x2 hi = __builtin_amdgcn_cvt_pk_f32_fp8((int)packed, true);   // bytes 2,3
  acc[0] += w * lo[0];
  acc[1] += w * lo[1];
  acc[2] += w * hi[0];
  acc[3] += w * hi[1];
#else
  acc[0] += w * fp8_to_f32((unsigned char)(packed & 0xff));
  acc[1] += w * fp8_to_f32((unsigned char)((packed >> 8) & 0xff));
  acc[2] += w * fp8_to_f32((unsigned char)((packed >> 16) & 0xff));
  acc[3] += w * fp8_to_f32((unsigned char)(packed >> 24));
#endif
}

// ---------------- CSR build ----------------
__global__ __launch_bounds__(256) void k_init_deg(int* deg, int N) {
  int n = blockIdx.x * 256 + threadIdx.x;
  if (n < N) deg[n] = 1;  // self-loop
}

__global__ __launch_bounds__(256) void k_count_deg(const int* __restrict__ ei,
                                                   int E, int* deg) {
  int e = blockIdx.x * 256 + threadIdx.x;
  if (e < E) atomicAdd(&deg[ei[E + e]], 1);
}

// --- 3-phase exclusive scan (R8: old single-block scan was 111us on 1 CU) ---
__global__ __launch_bounds__(256) void k_scan_partial(const int* __restrict__ deg,
                                                      int* __restrict__ blockSums,
                                                      int N) {
  __shared__ int sh[256];
  int t = threadIdx.x, b = blockIdx.x;
  int base = (b * 256 + t) * SCAN_CH;
  int s = 0;
#pragma unroll
  for (int j = 0; j < SCAN_CH; j++) {
    int idx = base + j;
    if (idx < N) s += deg[idx];
  }
  sh[t] = s;
  __syncthreads();
  for (int off = 128; off > 0; off >>= 1) {
    if (t < off) sh[t] += sh[t + off];
    __syncthreads();
  }
  if (t == 0) blockSums[b] = sh[0];
}

__global__ __launch_bounds__(256) void k_scan_blocksums(
    const int* __restrict__ blockSums, int* __restrict__ blockOffs,
    int* __restrict__ rowptr, int nb, int N) {
  __shared__ int sh[256];
  int t = threadIdx.x;
  int v = (t < nb) ? blockSums[t] : 0;
  sh[t] = v;
  __syncthreads();
  for (int off = 1; off < 256; off <<= 1) {
    int u = (t >= off) ? sh[t - off] : 0;
    __syncthreads();
    sh[t] += u;
    __syncthreads();
  }
  if (t < nb) blockOffs[t] = sh[t] - v;  // exclusive
  if (t == nb - 1) rowptr[N] = sh[t];    // total
}

__global__ __launch_bounds__(256) void k_scan_final(const int* __restrict__ deg,
                                                    const int* __restrict__ blockOffs,
                                                    int* __restrict__ rowptr,
                                                    int* __restrict__ cursor, int N) {
  __shared__ int sh[256];
  int t = threadIdx.x, b = blockIdx.x;
  int base = (b * 256 + t) * SCAN_CH;
  int vals[SCAN_CH];
  int s = 0;
#pragma unroll
  for (int j = 0; j < SCAN_CH; j++) {
    int idx = base + j;
    vals[j] = (idx < N) ? deg[idx] : 0;
    s += vals[j];
  }
  sh[t] = s;
  __syncthreads();
  for (int off = 1; off < 256; off <<= 1) {
    int u = (t >= off) ? sh[t - off] : 0;
    __syncthreads();
    sh[t] += u;
    __syncthreads();
  }
  int run = blockOffs[b] + sh[t] - s;  // exclusive prefix for this thread
#pragma unroll
  for (int j = 0; j < SCAN_CH; j++) {
    int idx = base + j;
    if (idx < N) {
      rowptr[idx] = run;
      cursor[idx] = run;
      run += vals[j];
    }
  }
}

// dst-striped scatter (R15/R21). Grid = 8 stripes x nch chunks; stripe =
// bid&7 (matches HW round-robin block->XCD, heuristic only). Single 4B
// src store per edge (R21: dst never read downstream).
__global__ __launch_bounds__(256) void k_scatter2(const int* __restrict__ ei,
                                                  int E, int N, int* cursor,
                                                  int* __restrict__ col_s,
                                                  int chunkSz) {
  int stripe = blockIdx.x & 7;
  int chunk = blockIdx.x >> 3;
  int lo = (int)(((long long)N * stripe) >> 3);
  int hi = (int)(((long long)N * (stripe + 1)) >> 3);
  int base = chunk * chunkSz;
  int end = base + chunkSz;
  int total = E + N;
  if (end > total) end = total;
  for (int i = base + threadIdx.x; i < end; i += 256) {
    int d = (i < E) ? ei[E + i] : (i - E);
    if (d < lo || d >= hi) continue;
    int s = (i < E) ? ei[i] : d;
    int pos = atomicAdd(&cursor[d], 1);
    col_s[pos] = s;
  }
}

// ---------------- cast prep (plain bf16) ----------------
__global__ __launch_bounds__(256) void k_cast(const float* __restrict__ in,
                                              __bf16* __restrict__ oh, int n4) {
  int i = blockIdx.x * 256 + threadIdx.x;
  if (i >= n4) return;
  float4 v = ((const float4*)in)[i];
  bf16x4 h;
  h[0] = (__bf16)v.x;
  h[1] = (__bf16)v.y;
  h[2] = (__bf16)v.z;
  h[3] = (__bf16)v.w;
  ((bf16x4*)oh)[i] = h;
}

// W [K][Nc] fp32 -> WT [Nc][K] plain bf16.
__global__ __launch_bounds__(256) void k_wprep(const float* __restrict__ W,
                                               __bf16* __restrict__ WTh,
                                               int K, int Nc) {
  int i = blockIdx.x * 256 + threadIdx.x;  // i = n*K + k
  if (i >= K * Nc) return;
  int n = i / K, k = i - n * K;
  WTh[i] = (__bf16)W[k * Nc + n];
}

// ------- LDS-shared MFMA GEMM + fused att dots (layers 1/2, R19/R21) -----
// C = Ah @ Bh, plain bf16. Block = 64 rows x 256 cols (782 blocks, 4 waves).
// Stage the WHOLE 64x256 A-strip (32KB, fragment-ordered) up front, ONE
// barrier, barrier-free k-loop (4 B-loads + 4 LDS reads + 16 MFMAs/step).
// Epilogue: global C stores; then barrier, spill h bf16 into sA (row-major
// [64][256]), barrier, 512 (row,head) att-dot tasks from LDS -> aS/aD.
// Wave w owns cols 64w..64w+63 = heads 2w,2w+1 — but the LDS spill makes
// all rows/heads visible to all threads, so tasks are split evenly.
// mfma_f32_16x16x32_bf16 (m89-verified): A: m=lane&15,k=quad*8+j;
// B: n=lane&15,k=quad*8+j (from WT); C/D: row=quad*4+reg, col=lane&15.
__global__ __launch_bounds__(256) void k_gemm_att(
    const __bf16* __restrict__ Ah, const __bf16* __restrict__ BTh,
    const float* __restrict__ attS, const float* __restrict__ attD,
    __bf16* __restrict__ Ch, unsigned char* __restrict__ Cf8,
    float* __restrict__ aS, float* __restrict__ aD, int M, int K) {
  constexpr int NcFull = 256;
  __shared__ __bf16 sA[64 * 256];  // 32 KB; reused for h spill after k-loop
  __shared__ float sAttS[256], sAttD[256];
  int tid = threadIdx.x;
  int lane = tid & 63, wave = tid >> 6;
  int quad = lane >> 4, l16 = lane & 15;
  int m0 = blockIdx.x * 64;
  int col0 = wave * 64;
  sAttS[tid] = attS[tid];  // 8 heads x 32 ch
  sAttD[tid] = attD[tid];
  // ---- stage all of A (8 rounds, coalesced, fragment-ordered) ----
  int srow = tid >> 2;                  // 0..63
  int mtw = srow >> 4, l16w = srow & 15;
  int arow = min(m0 + srow, M - 1);     // clamp: rows >= M never stored
  const __bf16* ag = Ah + (size_t)arow * K;
#pragma unroll
  for (int r = 0; r < 8; r++) {
    int c = (tid & 3) + r * 4;          // 8-elem chunk 0..31
    int s = c >> 2, q = c & 3;
    int slot = (((s * 4 + mtw) * 4 + q) * 16 + l16w) * 8;
    *(bf16x8*)(sA + slot) = *(const bf16x8*)(ag + c * 8);
  }
  __syncthreads();
  const __bf16* brh = BTh + (size_t)(col0 + l16) * K + quad * 8;
  f32x4 acc[4][4];  // [mt][nt]
#pragma unroll
  for (int mt = 0; mt < 4; mt++)
#pragma unroll
    for (int t = 0; t < 4; t++) acc[mt][t] = (f32x4){0.f, 0.f, 0.f, 0.f};
  for (int s = 0; s < 8; s++) {  // k0 = s*32; no barriers inside
    bf16x8 b_h[4];
#pragma unroll
    for (int t = 0; t < 4; t++)
      b_h[t] = *(const bf16x8*)(brh + (size_t)t * 16 * K + s * 32);
    bf16x8 a_h[4];
#pragma unroll
    for (int mt = 0; mt < 4; mt++)
      a_h[mt] = *(const bf16x8*)(sA + (((s * 4 + mt) * 4 + quad) * 16 + l16) * 8);
#pragma unroll
    for (int t = 0; t < 4; t++) {
#pragma unroll
      for (int mt = 0; mt < 4; mt++) {
        acc[mt][t] = __builtin_amdgcn_mfma_f32_16x16x32_bf16(a_h[mt], b_h[t], acc[mt][t], 0, 0, 0);
      }
    }
  }
  __syncthreads();  // all sA (A-tile) reads done; safe to overwrite with h
#pragma unroll
  for (int mt = 0; mt < 4; mt++) {
#pragma unroll
    for (int t = 0; t < 4; t++) {
#pragma unroll
      for (int r = 0; r < 4; r++) {
        int row = mt * 16 + quad * 4 + r;
        int m = m0 + row;
        int colq = t * 16 + l16;
        __bf16 hv = (__bf16)acc[mt][t][r];
        sA[row * 256 + col0 + colq] = hv;  // h spill (row-major)
        if (m < M) {
          size_t o = (size_t)m * NcFull + col0 + colq;
          Ch[o] = hv;
          Cf8[o] = f32_to_fp8(acc[mt][t][r]);
        }
      }
    }
  }
  __syncthreads();
  // ---- att dots: 512 tasks = (row 0..63, head 0..7), 2 per thread ----
#pragma unroll
  for (int u = 0; u < 2; u++) {
    int task = tid + u * 256;
    int row = task >> 3, h = task & 7;
    const __bf16* hr = sA + row * 256 + h * 32;
    float ss = 0.f, dd = 0.f;
#pragma unroll
    for (int k = 0; k < 4; k++) {
      bf16x8 a = *(const bf16x8*)(hr + k * 8);
#pragma unroll
      for (int j = 0; j < 8; j++) {
        float v = (float)a[j];
        ss += v * sAttS[h * 32 + k * 8 + j];
        dd += v * sAttD[h * 32 + k * 8 + j];
      }
    }
    int m = m0 + row;
    if (m < M) {
      aS[(size_t)m * 8 + h] = ss;
      aD[(size_t)m * 8 + h] = dd;
    }
  }
}

// ---------------- MFMA GEMM, no-LDS (layer 3): Ah @ Bh ------------------
template <int NT, int MT>
__global__ __launch_bounds__(256) void k_gemm_split(
    const __bf16* __restrict__ Ah, const __bf16* __restrict__ BTh,
    __bf16* __restrict__ Ch, int M, int K, int NcFull) {
  int lane = threadIdx.x & 63;
  int wave = threadIdx.x >> 6;
  int quad = lane >> 4;
  int l16 = lane & 15;
  int m0 = blockIdx.y * (64 * MT) + wave * (16 * MT);
  int col0 = blockIdx.x * (NT * 16);
  const __bf16* arh[MT];
#pragma unroll
  for (int mt = 0; mt < MT; mt++) {
    int am = min(m0 + mt * 16 + l16, M - 1);
    arh[mt] = Ah + (size_t)am * K + quad * 8;
  }
  const __bf16* brh = BTh + (size_t)(col0 + l16) * K + quad * 8;
  f32x4 acc[MT][NT];
#pragma unroll
  for (int mt = 0; mt < MT; mt++)
#pragma unroll
    for (int t = 0; t < NT; t++) acc[mt][t] = (f32x4){0.f, 0.f, 0.f, 0.f};
  for (int k0 = 0; k0 < K; k0 += 32) {
    bf16x8 a_h[MT], b_h[NT];
#pragma unroll
    for (int mt = 0; mt < MT; mt++) {
      a_h[mt] = *(const bf16x8*)(arh[mt] + k0);
    }
#pragma unroll
    for (int t = 0; t < NT; t++)
      b_h[t] = *(const bf16x8*)(brh + (size_t)t * 16 * K + k0);
#pragma unroll
    for (int t = 0; t < NT; t++) {
#pragma unroll
      for (int mt = 0; mt < MT; mt++) {
        acc[mt][t] = __builtin_amdgcn_mfma_f32_16x16x32_bf16(a_h[mt], b_h[t], acc[mt][t], 0, 0, 0);
      }
    }
  }
#pragma unroll
  for (int mt = 0; mt < MT; mt++) {
#pragma unroll
    for (int t = 0; t < NT; t++) {
#pragma unroll
      for (int r = 0; r < 4; r++) {
        int m = m0 + mt * 16 + quad * 4 + r;
        if (m < M)
          Ch[(size_t)m * NcFull + col0 + t * 16 + l16] = (__bf16)acc[mt][t][r];
      }
    }
  }
}

// ---------------- attention dots (layer 3, H=1) ----------------
__global__ __launch_bounds__(256) void k_att(const __bf16* __restrict__ Hh,
                                             const float* __restrict__ attS,
                                             const float* __restrict__ attD,
                                             float* __restrict__ aS,
                                             float* __restrict__ aD, int NH, int H) {
  int idx = blockIdx.x * 256 + threadIdx.x;
  if (idx >= NH) return;
  int h = idx % H;
  const bf16x8* hv = (const bf16x8*)(Hh + (size_t)idx * 32);
  const float* sv = attS + h * 32;
  const float* dv = attD + h * 32;
  float ss = 0.f, dd = 0.f;
#pragma unroll
  for (int k = 0; k < 4; k++) {
    bf16x8 a = hv[k];
#pragma unroll
    for (int j = 0; j < 8; j++) {
      float v = (float)a[j];
      ss += v * sv[k * 8 + j];
      dd += v * dv[k * 8 + j];
    }
  }
  aS[idx] = ss;
  aD[idx] = dd;
}

// ---------------- GAT aggregation, H=8, fused alpha (R20/R21) ------------
// wave per node. lane = (edge-group g = lane>>4, channel-block c = lane&15:
// 16 fp8 channels = one dwordx4). One gather instruction serves 4 edges.
// w = exp(leaky(aS[s*8+head] + aD[n*8+head])) inline (head = c>>1; aS
// 1.6MB L2-resident). Cross-group shfl reduce (xor 16,32), then g==0 lanes
// do bias+ELU and write 32B each.
__global__ __launch_bounds__(256) void k_gat_agg8f(
    const unsigned char* __restrict__ Hf8, const int* __restrict__ rowptr,
    const int* __restrict__ col_s, const float* __restrict__ aS,
    const float* __restrict__ aD, const float* __restrict__ bias,
    __bf16* __restrict__ outh, int N) {
  int wid = (blockIdx.x * blockDim.x + threadIdx.x) >> 6;
  int lane = threadIdx.x & 63;
  if (wid >= N) return;
  int n = wid;
  int row0 = rowptr[n];
  int deg = rowptr[n + 1] - row0;
  int g = lane >> 4;   // edge group 0..3
  int c = lane & 15;   // channel block (16 fp8 = 16B)
  int head = c >> 1;
  float ad = aD[(size_t)n * 8 + head];
  f32x4 acc0 = (f32x4){0.f, 0.f, 0.f, 0.f};
  f32x4 acc1 = (f32x4){0.f, 0.f, 0.f, 0.f};
  f32x4 acc2 = (f32x4){0.f, 0.f, 0.f, 0.f};
  f32x4 acc3 = (f32x4){0.f, 0.f, 0.f, 0.f};
  float den = 0.f;
  int dm1 = deg - 1;
  for (int i = 0; i < deg; i += 8) {
    int e0 = i + g, e1 = i + 4 + g;
    int sl0 = row0 + min(e0, dm1);
    int sl1 = row0 + min(e1, dm1);
    int s0 = col_s[sl0];
    int s1 = col_s[sl1];
    uint4 p0 = *(const uint4*)(Hf8 + (size_t)s0 * 256 + c * 16);
    uint4 p1 = *(const uint4*)(Hf8 + (size_t)s1 * 256 + c * 16);
    float w0 = 0.f, w1 = 0.f;
    if (e0 < deg) {
      float x = aS[(size_t)s0 * 8 + head] + ad;
      x = (x > 0.f) ? x : 0.2f * x;
      w0 = __expf(x);
    }
    if (e1 < deg) {
      float x = aS[(size_t)s1 * 8 + head] + ad;
      x = (x > 0.f) ? x : 0.2f * x;
      w1 = __expf(x);
    }
    den += w0 + w1;
    fma_fp8x4(acc0, w0, p0.x);
    fma_fp8x4(acc1, w0, p0.y);
    fma_fp8x4(acc2, w0, p0.z);
    fma_fp8x4(acc3, w0, p0.w);
    fma_fp8x4(acc0, w1, p1.x);
    fma_fp8x4(acc1, w1, p1.y);
    fma_fp8x4(acc2, w1, p1.z);
    fma_fp8x4(acc3, w1, p1.w);
  }
  // reduce across the 4 edge-groups (lane bits 4,5)
#pragma unroll
  for (int off = 16; off < 64; off <<= 1) {
#pragma unroll
    for (int j = 0; j < 4; j++) {
      acc0[j] += __shfl_xor(acc0[j], off, 64);
      acc1[j] += __shfl_xor(acc1[j], off, 64);
      acc2[j] += __shfl_xor(acc2[j], off, 64);
      acc3[j] += __shfl_xor(acc3[j], off, 64);
    }
    den += __shfl_xor(den, off, 64);
  }
  if (g == 0) {
    float rsv = 1.f / den;  // deg >= 1 (self-loop), den > 0
    const float4* bp = (const float4*)(bias + c * 16);
    float4 b0 = bp[0], b1 = bp[1], b2 = bp[2], b3 = bp[3];
    bf16x8 o0, o1;
#pragma unroll
    for (int j = 0; j < 4; j++) {
      float v0 = acc0[j] * rsv + ((const float*)&b0)[j];
      float v1 = acc1[j] * rsv + ((const float*)&b1)[j];
      float v2 = acc2[j] * rsv + ((const float*)&b2)[j];
      float v3 = acc3[j] * rsv + ((const float*)&b3)[j];
      v0 = (v0 > 0.f) ? v0 : (__expf(v0) - 1.f);  // ELU
      v1 = (v1 > 0.f) ? v1 : (__expf(v1) - 1.f);
      v2 = (v2 > 0.f) ? v2 : (__expf(v2) - 1.f);
      v3 = (v3 > 0.f) ? v3 : (__expf(v3) - 1.f);
      o0[j] = (__bf16)v0;
      o0[j + 4] = (__bf16)v1;
      o1[j] = (__bf16)v2;
      o1[j + 4] = (__bf16)v3;
    }
    *(bf16x8*)(outh + (size_t)n * 256 + c * 16) = o0;
    *(bf16x8*)(outh + (size_t)n * 256 + c * 16 + 8) = o1;
  }
}

// ---------------- GAT aggregation, H=1, fused alpha (layer 3) -----------
__global__ __launch_bounds__(256) void k_gat_agg1f(
    const __bf16* __restrict__ Hh, const int* __restrict__ rowptr,
    const int* __restrict__ col_s, const float* __restrict__ aS,
    const float* __restrict__ aD, const float* __restrict__ bias,
    float* __restrict__ out, int N) {
  int wid = (blockIdx.x * blockDim.x + threadIdx.x) >> 6;
  int lane = threadIdx.x & 63;
  if (wid >= N) return;
  int n = wid;
  int row0 = rowptr[n];
  int deg = rowptr[n + 1] - row0;
  int eo = lane >> 3;
  int cl = lane & 7;
  float ad = aD[n];
  f32x4 acc = (f32x4){0.f, 0.f, 0.f, 0.f};
  float den = 0.f;
  for (int i = eo; i < deg; i += 8) {
    int slot = row0 + i;
    int src = col_s[slot];
    float x = aS[src] + ad;
    x = (x > 0.f) ? x : 0.2f * x;
    float w = __expf(x);
    den += w;
    bf16x4 hv = *(const bf16x4*)(Hh + (size_t)src * 32 + cl * 4);
#pragma unroll
    for (int j = 0; j < 4; j++) acc[j] += w * (float)hv[j];
  }
#pragma unroll
  for (int off = 8; off < 64; off <<= 1) {
#pragma unroll
    for (int j = 0; j < 4; j++) acc[j] += __shfl_xor(acc[j], off, 64);
    den += __shfl_xor(den, off, 64);
  }
  if (eo == 0) {
    float rsv = 1.f / den;
#pragma unroll
    for (int j = 0; j < 4; j++)
      out[(size_t)n * 32 + cl * 4 + j] = acc[j] * rsv + bias[cl * 4 + j];
  }
}

// ---------------- fused mean-pool + linear ----------------
__global__ __launch_bounds__(256) void k_pool_final(
    const float* __restrict__ h, const int* __restrict__ batch,
    const float* __restrict__ linW, const float* __restrict__ linb,
    float* __restrict__ out, int N) {
  __shared__ float sh[256];
  int g = blockIdx.x;
  int tid = threadIdx.x;
  int grp = tid >> 5, c = tid & 31;
  int lo = 0, hi = N;
  while (lo < hi) { int mid = (lo + hi) >> 1; if (batch[mid] < g) lo = mid + 1; else hi = mid; }
  int start = lo;
  hi = N;
  while (lo < hi) { int mid = (lo + hi) >> 1; if (batch[mid] < g + 1) lo = mid + 1; else hi = mid; }
  int end = lo;
  float acc = 0.f;
  for (int n = start + grp; n < end; n += 8) acc += h[(size_t)n * 32 + c];
  sh[tid] = acc;
  __syncthreads();
  if (tid < 32) {
    float s = 0.f;
#pragma unroll
    for (int j = 0; j < 8; j++) s += sh[j * 32 + tid];
    float v = s * linW[tid];
#pragma unroll
    for (int off = 16; off > 0; off >>= 1) v += __shfl_xor(v, off, 64);
    if (tid == 0) {
      float cnt = (float)(end - start);
      out[g] = v / fmaxf(cnt, 1.f) + linb[0];
    }
  }
}

extern "C" void kernel_launch(void* const* d_in, const int* in_sizes, int n_in,
                              void* d_out, int out_size, void* d_ws, size_t ws_size,
                              hipStream_t stream) {
  const float* x = (const float*)d_in[0];
  const int* ei = (const int*)d_in[1];
  const int* batch = (const int*)d_in[2];
  const float* W1 = (const float*)d_in[3];
  const float* as1 = (const float*)d_in[4];
  const float* ad1 = (const float*)d_in[5];
  const float* b1 = (const float*)d_in[6];
  const float* W2 = (const float*)d_in[7];
  const float* as2 = (const float*)d_in[8];
  const float* ad2 = (const float*)d_in[9];
  const float* b2 = (const float*)d_in[10];
  const float* W3 = (const float*)d_in[11];
  const float* as3 = (const float*)d_in[12];
  const float* ad3 = (const float*)d_in[13];
  const float* b3 = (const float*)d_in[14];
  const float* linW = (const float*)d_in[15];
  const float* linb = (const float*)d_in[16];

  const int N = in_sizes[0] / 256;
  const int E = in_sizes[1] / 2;
  const int NUM_GRAPHS = 64;
  float* out = (float*)d_out;

  char* ws = (char*)d_ws;
  size_t off = 0;
  auto alloc = [&](size_t bytes) -> void* {
    void* p = ws + off;
    off += (bytes + 255) & ~(size_t)255;
    return p;
  };
  __bf16* Hh = (__bf16*)alloc((size_t)N * 256 * 2);  // GEMM h out (bf16)
  unsigned char* Hf8 = (unsigned char*)alloc((size_t)N * 256);  // fp8 copy
  __bf16* Ah = (__bf16*)alloc((size_t)N * 256 * 2);  // GEMM A in (bf16)
  float* aS = (float*)alloc((size_t)N * 8 * 4);
  float* aD = (float*)alloc((size_t)N * 8 * 4);
  int* deg = (int*)alloc((size_t)N * 4);
  int* rowptr = (int*)alloc((size_t)(N + 1) * 4);
  int* cursor = (int*)alloc((size_t)(N + 1) * 4);
  int* col_s = (int*)alloc((size_t)(E + N) * 4);  // src per CSR slot
  int* blockSums = (int*)alloc(256 * 4);
  int* blockOffs = (int*)alloc(256 * 4);
  __bf16* WT1h = (__bf16*)alloc(256 * 256 * 2);
  __bf16* WT2h = (__bf16*)alloc(256 * 256 * 2);
  __bf16* WT3h = (__bf16*)alloc(32 * 256 * 2);
  // h3agg reuses Ah (GEMM3 already consumed Ah when agg3 writes)
  float* h3agg = (float*)Ah;

  // --- preps: x cast + W transposes + CSR build ---
  k_cast<<<(N * 64 + 255) / 256, 256, 0, stream>>>(x, Ah, N * 64);
  k_wprep<<<(256 * 256 + 255) / 256, 256, 0, stream>>>(W1, WT1h, 256, 256);
  k_wprep<<<(256 * 256 + 255) / 256, 256, 0, stream>>>(W2, WT2h, 256, 256);
  k_wprep<<<(256 * 32 + 255) / 256, 256, 0, stream>>>(W3, WT3h, 256, 32);
  k_init_deg<<<(N + 255) / 256, 256, 0, stream>>>(deg, N);
  k_count_deg<<<(E + 255) / 256, 256, 0, stream>>>(ei, E, deg);
  const int nb = (N + 256 * SCAN_CH - 1) / (256 * SCAN_CH);  // 49 <= 256
  k_scan_partial<<<nb, 256, 0, stream>>>(deg, blockSums, N);
  k_scan_blocksums<<<1, 256, 0, stream>>>(blockSums, blockOffs, rowptr, nb, N);
  k_scan_final<<<nb, 256, 0, stream>>>(deg, blockOffs, rowptr, cursor, N);
  {
    const int totalItems = E + N;
    const int nch = 256;  // chunks per stripe; grid = 8*256 = 2048 blocks
    const int chunkSz = (totalItems + nch - 1) / nch;
    k_scatter2<<<8 * nch, 256, 0, stream>>>(ei, E, N, cursor, col_s, chunkSz);
  }

  const int aggBlocks = (N + 3) / 4;
  const int gemmBlocks = (N + 63) / 64;  // 64 rows/block, full 256-col width
  dim3 g3(1, (N + 63) / 64);

  // --- layer 1 ---
  k_gemm_att<<<gemmBlocks, 256, 0, stream>>>(Ah, WT1h, as1, ad1, Hh, Hf8,
                                             aS, aD, N, 256);
  k_gat_agg8f<<<aggBlocks, 256, 0, stream>>>(Hf8, rowptr, col_s, aS, aD, b1,
                                             Ah, N);
  // --- layer 2 ---
  k_gemm_att<<<gemmBlocks, 256, 0, stream>>>(Ah, WT2h, as2, ad2, Hh, Hf8,
                                             aS, aD, N, 256);
  k_gat_agg8f<<<aggBlocks, 256, 0, stream>>>(Hf8, rowptr, col_s, aS, aD, b2,
                                             Ah, N);
  // --- layer 3 (H=1, bf16 gather) ---
  k_gemm_split<2, 1><<<g3, 256, 0, stream>>>(Ah, WT3h, Hh, N, 256, 32);
  k_att<<<(N + 255) / 256, 256, 0, stream>>>(Hh, as3, ad3, aS, aD, N, 1);
  k_gat_agg1f<<<aggBlocks, 256, 0, stream>>>(Hh, rowptr, col_s, aS, aD, b3,
                                             h3agg, N);
  // --- pool + final ---
  k_pool_final<<<NUM_GRAPHS, 256, 0, stream>>>(h3agg, batch, linW, linb, out, N);
}